// Round 1
// baseline (679.747 us; speedup 1.0000x reference)
//
#include <hip/hip_runtime.h>
#include <hip/hip_bf16.h>
#include <math.h>

// Mamba forward, B=1, L=2048, H=1024, DI=2048, N=16, R=64, K=4
#define H_DIM 1024
#define DI    2048
#define NS    16
#define RR    64
#define LL    2048
#define NC    32   // chunks for the parallel scan
#define CL    64   // chunk length = LL/NC

__device__ __forceinline__ float silu_f(float x)  { return x / (1.f + __expf(-x)); }
__device__ __forceinline__ float softplus_f(float x) {
    // stable: max(x,0) + log1p(exp(-|x|))
    return fmaxf(x, 0.f) + log1pf(__expf(-fabsf(x)));
}

// ---------------------------------------------------------------------------
// Generic C[M,N] = A[M,K](lda) @ W[N,K]^T + bias, optional softplus.
// 64x64 output tile per 256-thread block, 4x4 per thread, K-tile 16.
// ---------------------------------------------------------------------------
template<int BIAS, int ACT>
__global__ __launch_bounds__(256) void gemm_nt(
    const float* __restrict__ A, int lda,
    const float* __restrict__ W,        // [N][K] row-major
    const float* __restrict__ bias,
    float* __restrict__ C, int ldc,
    int M, int N, int K)
{
    __shared__ float As[16][68];   // [k][m] transposed; pad 68 keeps float4 reads aligned
    __shared__ float Ws[16][68];   // [k][n]
    const int tid = threadIdx.x;
    const int tx = tid & 15, ty = tid >> 4;
    const int m0 = blockIdx.y * 64, n0 = blockIdx.x * 64;
    const int r  = tid >> 2;           // 0..63 (row within tile for staging)
    const int c4 = (tid & 3) << 2;     // 0,4,8,12 (k offset for staging)
    const int arow = m0 + r;           // M is always a multiple of 64 here
    const int wrow = n0 + r;

    float acc[4][4] = {};

    for (int k0 = 0; k0 < K; k0 += 16) {
        float4 av = *(const float4*)&A[(size_t)arow * lda + k0 + c4];
        float4 wv = make_float4(0.f, 0.f, 0.f, 0.f);
        if (wrow < N) wv = *(const float4*)&W[(size_t)wrow * K + k0 + c4];
        As[c4+0][r] = av.x; As[c4+1][r] = av.y; As[c4+2][r] = av.z; As[c4+3][r] = av.w;
        Ws[c4+0][r] = wv.x; Ws[c4+1][r] = wv.y; Ws[c4+2][r] = wv.z; Ws[c4+3][r] = wv.w;
        __syncthreads();
        #pragma unroll
        for (int k = 0; k < 16; ++k) {
            float4 a = *(const float4*)&As[k][ty * 4];
            float4 b = *(const float4*)&Ws[k][tx * 4];
            float ar[4] = {a.x, a.y, a.z, a.w};
            float br[4] = {b.x, b.y, b.z, b.w};
            #pragma unroll
            for (int i = 0; i < 4; ++i)
                #pragma unroll
                for (int j = 0; j < 4; ++j)
                    acc[i][j] = fmaf(ar[i], br[j], acc[i][j]);
        }
        __syncthreads();
    }

    #pragma unroll
    for (int i = 0; i < 4; ++i) {
        const int row = m0 + ty * 4 + i;
        #pragma unroll
        for (int j = 0; j < 4; ++j) {
            const int col = n0 + tx * 4 + j;
            if (col < N) {
                float v = acc[i][j];
                if (BIAS) v += bias[col];
                if (ACT == 1) v = softplus_f(v);
                C[(size_t)row * ldc + col] = v;
            }
        }
    }
}

// ---------------------------------------------------------------------------
// Causal depthwise conv (K=4) + bias + silu.  xr = [L][2*DI], use cols 0..DI-1.
// ---------------------------------------------------------------------------
__global__ __launch_bounds__(256) void conv_silu_k(
    const float* __restrict__ xr, const float* __restrict__ cw,
    const float* __restrict__ cb, float* __restrict__ xs)
{
    const int idx = blockIdx.x * 256 + threadIdx.x;   // over L*DI
    const int l = idx >> 11;                          // / DI
    const int d = idx & (DI - 1);
    float acc = cb[d];
    const float w0 = cw[d*4+0], w1 = cw[d*4+1], w2 = cw[d*4+2], w3 = cw[d*4+3];
    if (l >= 3) acc = fmaf(xr[(size_t)(l-3)*(2*DI) + d], w0, acc);
    if (l >= 2) acc = fmaf(xr[(size_t)(l-2)*(2*DI) + d], w1, acc);
    if (l >= 1) acc = fmaf(xr[(size_t)(l-1)*(2*DI) + d], w2, acc);
    acc = fmaf(xr[(size_t)l*(2*DI) + d], w3, acc);
    xs[idx] = silu_f(acc);
}

// ---------------------------------------------------------------------------
// Scan phase 1: per (chunk c, channel d) local scan with h=0 start.
// Emits per-chunk total A-product P and local final state S.
// ---------------------------------------------------------------------------
__global__ __launch_bounds__(256) void scan1_k(
    const float* __restrict__ delta, const float* __restrict__ xs,
    const float* __restrict__ A_log, const float* __restrict__ xdbl,
    float* __restrict__ P, float* __restrict__ S)
{
    const int d = blockIdx.x * 256 + threadIdx.x;
    const int c = blockIdx.y;
    float A[NS];
    #pragma unroll
    for (int n = 0; n < NS; ++n) A[n] = -__expf(A_log[d * NS + n]);
    float h[NS] = {};
    float ap[NS];
    #pragma unroll
    for (int n = 0; n < NS; ++n) ap[n] = 1.f;

    const int l0 = c * CL;
    for (int l = l0; l < l0 + CL; ++l) {
        const float dt = delta[(size_t)l * DI + d];
        const float u  = xs[(size_t)l * DI + d];
        const float du = dt * u;
        #pragma unroll
        for (int n = 0; n < NS; ++n) {
            const float Bn = xdbl[(size_t)l * 96 + RR + n];
            const float dA = __expf(dt * A[n]);
            h[n]  = fmaf(dA, h[n], du * Bn);
            ap[n] *= dA;
        }
    }
    const size_t base = ((size_t)c * DI + d) * NS;
    #pragma unroll
    for (int n = 0; n < NS; ++n) { P[base + n] = ap[n]; S[base + n] = h[n]; }
}

// ---------------------------------------------------------------------------
// Scan phase 2: sequential scan over the NC chunks, one thread per (d,n).
// Writes the EXCLUSIVE prefix state entering each chunk.
// ---------------------------------------------------------------------------
__global__ __launch_bounds__(256) void scan2_k(
    const float* __restrict__ P, const float* __restrict__ S, float* __restrict__ Hp)
{
    const int idx = blockIdx.x * 256 + threadIdx.x;   // over DI*NS
    float h = 0.f;
    for (int c = 0; c < NC; ++c) {
        const size_t o = (size_t)c * DI * NS + idx;
        Hp[o] = h;
        h = fmaf(P[o], h, S[o]);
    }
}

// ---------------------------------------------------------------------------
// Scan phase 3: replay with the prefix state, emit y = (h.C + xs*D) * silu(res).
// y may alias delta (each element is read before it is written by the same thread).
// ---------------------------------------------------------------------------
__global__ __launch_bounds__(256) void scan3_k(
    const float* delta, const float* __restrict__ xs,
    const float* __restrict__ A_log, const float* __restrict__ xdbl,
    const float* __restrict__ Hp, const float* __restrict__ xr,
    const float* __restrict__ Dp, float* y)
{
    const int d = blockIdx.x * 256 + threadIdx.x;
    const int c = blockIdx.y;
    float A[NS];
    #pragma unroll
    for (int n = 0; n < NS; ++n) A[n] = -__expf(A_log[d * NS + n]);
    float h[NS];
    const size_t base = ((size_t)c * DI + d) * NS;
    #pragma unroll
    for (int n = 0; n < NS; ++n) h[n] = Hp[base + n];
    const float Dd = Dp[d];

    const int l0 = c * CL;
    for (int l = l0; l < l0 + CL; ++l) {
        const float dt = delta[(size_t)l * DI + d];
        const float u  = xs[(size_t)l * DI + d];
        const float du = dt * u;
        float acc = 0.f;
        #pragma unroll
        for (int n = 0; n < NS; ++n) {
            const float Bn = xdbl[(size_t)l * 96 + RR + n];
            const float Cn = xdbl[(size_t)l * 96 + RR + NS + n];
            const float dA = __expf(dt * A[n]);
            h[n] = fmaf(dA, h[n], du * Bn);
            acc  = fmaf(h[n], Cn, acc);
        }
        float yv = fmaf(u, Dd, acc);
        const float r = xr[(size_t)l * (2*DI) + DI + d];
        yv *= silu_f(r);
        y[(size_t)l * DI + d] = yv;
    }
}

// ---------------------------------------------------------------------------
extern "C" void kernel_launch(void* const* d_in, const int* in_sizes, int n_in,
                              void* d_out, int out_size, void* d_ws, size_t ws_size,
                              hipStream_t stream)
{
    const float* x        = (const float*)d_in[0];   // [L][H]
    const float* in_w     = (const float*)d_in[1];   // [2DI][H]
    const float* in_b     = (const float*)d_in[2];   // [2DI]
    const float* conv_w   = (const float*)d_in[3];   // [DI][1][4]
    const float* conv_b   = (const float*)d_in[4];   // [DI]
    const float* xproj_w  = (const float*)d_in[5];   // [96][DI]
    const float* dtproj_w = (const float*)d_in[6];   // [DI][R]
    const float* dtproj_b = (const float*)d_in[7];   // [DI]
    const float* A_log    = (const float*)d_in[8];   // [DI][N]
    const float* Dp       = (const float*)d_in[9];   // [DI]
    const float* outw     = (const float*)d_in[10];  // [H][DI]
    float* out = (float*)d_out;                      // [L][H]

    float* ws    = (float*)d_ws;
    float* xr    = ws;                                 // [L][2DI]   32 MB
    float* xs    = xr    + (size_t)LL * 2 * DI;        // [L][DI]    16 MB
    float* xdbl  = xs    + (size_t)LL * DI;            // [L][96]    0.75 MB
    float* delta = xdbl  + (size_t)LL * 96;            // [L][DI]    16 MB (y reuses this)
    float* P     = delta + (size_t)LL * DI;            // [NC][DI][NS] 4 MB
    float* S     = P     + (size_t)NC * DI * NS;       // 4 MB
    float* Hp    = S     + (size_t)NC * DI * NS;       // 4 MB
    // total ~77 MB of d_ws

    const dim3 blk(256);

    // 1) x_and_res = x @ in_proj_w^T + in_proj_b           [L][2DI]
    gemm_nt<1,0><<<dim3((2*DI)/64, LL/64), blk, 0, stream>>>(
        x, H_DIM, in_w, in_b, xr, 2*DI, LL, 2*DI, H_DIM);

    // 2) xs = silu(causal depthwise conv(xc) + conv_b)     [L][DI]
    conv_silu_k<<<dim3((LL*DI)/256), blk, 0, stream>>>(xr, conv_w, conv_b, xs);

    // 3) x_dbl = xs @ x_proj_w^T                           [L][96]
    gemm_nt<0,0><<<dim3(2, LL/64), blk, 0, stream>>>(
        xs, DI, xproj_w, nullptr, xdbl, 96, LL, 96, DI);

    // 4) delta = softplus(x_dbl[:, :64] @ dt_proj_w^T + dt_proj_b)   [L][DI]
    gemm_nt<1,1><<<dim3(DI/64, LL/64), blk, 0, stream>>>(
        xdbl, 96, dtproj_w, dtproj_b, delta, DI, LL, DI, RR);

    // 5-7) chunked associative scan
    scan1_k<<<dim3(DI/256, NC), blk, 0, stream>>>(delta, xs, A_log, xdbl, P, S);
    scan2_k<<<dim3((DI*NS)/256), blk, 0, stream>>>(P, S, Hp);
    scan3_k<<<dim3(DI/256, NC), blk, 0, stream>>>(delta, xs, A_log, xdbl, Hp, xr, Dp,
                                                  delta /* y in-place */);

    // 8) out = y @ out_proj_w^T                            [L][H]
    gemm_nt<0,0><<<dim3(H_DIM/64, LL/64), blk, 0, stream>>>(
        delta, DI, outw, nullptr, out, H_DIM, LL, H_DIM, DI);
}

// Round 2
// 400.507 us; speedup vs baseline: 1.6972x; 1.6972x over previous
//
#include <hip/hip_runtime.h>
#include <hip/hip_bf16.h>
#include <math.h>

// Mamba forward, B=1, L=2048, H=1024, DI=2048, N=16, R=64, K=4
#define H_DIM 1024
#define DI    2048
#define NS    16
#define RR    64
#define LL    2048
#define NC    32   // chunks for the parallel scan
#define CL    64   // chunk length = LL/NC

typedef __bf16 bf16x8 __attribute__((ext_vector_type(8)));
typedef __bf16 bf16x4 __attribute__((ext_vector_type(4)));
typedef float  f32x4  __attribute__((ext_vector_type(4)));

__device__ __forceinline__ float silu_f(float x)  { return x / (1.f + __expf(-x)); }
__device__ __forceinline__ float softplus_f(float x) {
    return fmaxf(x, 0.f) + log1pf(__expf(-fabsf(x)));
}

__device__ __forceinline__ void gload16(const void* g, void* l) {
    __builtin_amdgcn_global_load_lds(
        (const __attribute__((address_space(1))) void*)g,
        (__attribute__((address_space(3))) void*)l, 16, 0, 0);
}

// ---------------------------------------------------------------------------
// fp32 -> bf16 converter (n multiple of 1024, grid = n/1024)
// ---------------------------------------------------------------------------
__global__ __launch_bounds__(256) void f2b_k(const float* __restrict__ in,
                                             __bf16* __restrict__ out)
{
    const size_t i = ((size_t)blockIdx.x * 256 + threadIdx.x) * 4;
    float4 v = *(const float4*)&in[i];
    bf16x4 o;
    o[0] = (__bf16)v.x; o[1] = (__bf16)v.y; o[2] = (__bf16)v.z; o[3] = (__bf16)v.w;
    *(bf16x4*)&out[i] = o;
}

// ---------------------------------------------------------------------------
// bf16 MFMA GEMM: C[M,N] = A[M,K] @ W[N,K]^T (+bias)(+softplus), fp32 out.
// m97 structure: 128x128 tile, 4 waves, 4x4 frags of 16x16x32, BK=32,
// global_load_lds width 16, 2 barriers per K-step.
// M, N multiples of 128; K multiple of 32.  grid = (N/128, M/128), block 256.
// ---------------------------------------------------------------------------
template<int BIAS, int ACT>
__global__ __launch_bounds__(256) void gemm_bf16_nt(
    const __bf16* __restrict__ A, int lda,
    const __bf16* __restrict__ W, int ldw,
    const float* __restrict__ bias,
    float* __restrict__ C, int ldc,
    int K)
{
    __shared__ __bf16 smA[128 * 32];
    __shared__ __bf16 smB[128 * 32];
    const int t    = threadIdx.x;
    const int lane = t & 63;
    const int m0 = blockIdx.y * 128, n0 = blockIdx.x * 128;
    const int wr = ((t >> 6) >> 1) * 64;        // wave row offset (0/64)
    const int wc = ((t >> 6) & 1) * 64;         // wave col offset (0/64)

    // staging: chunk c = t (first) / t+256 (second); LDS byte off = c*16
    const int srow = t >> 2;                    // 0..63
    const int skof = (t & 3) * 8;               // 0/8/16/24
    const int lds_base = (t >> 6) * 512;        // elements (wave-uniform)

    // fragment LDS offsets (elements)
    const int offA = (wr + (lane & 15)) * 32 + ((lane >> 4) * 8);
    const int offB = (wc + (lane & 15)) * 32 + ((lane >> 4) * 8);

    f32x4 acc[4][4] = {};

    for (int k0 = 0; k0 < K; k0 += 32) {
        gload16(A + (size_t)(m0 + srow)      * lda + k0 + skof, &smA[lds_base]);
        gload16(A + (size_t)(m0 + 64 + srow) * lda + k0 + skof, &smA[2048 + lds_base]);
        gload16(W + (size_t)(n0 + srow)      * ldw + k0 + skof, &smB[lds_base]);
        gload16(W + (size_t)(n0 + 64 + srow) * ldw + k0 + skof, &smB[2048 + lds_base]);
        __syncthreads();   // drains vmcnt -> LDS tiles ready

        bf16x8 af[4], bfr[4];
        #pragma unroll
        for (int m = 0; m < 4; ++m) af[m]  = *(const bf16x8*)&smA[offA + m * 512];
        #pragma unroll
        for (int n = 0; n < 4; ++n) bfr[n] = *(const bf16x8*)&smB[offB + n * 512];
        #pragma unroll
        for (int m = 0; m < 4; ++m)
            #pragma unroll
            for (int n = 0; n < 4; ++n)
                acc[m][n] = __builtin_amdgcn_mfma_f32_16x16x32_bf16(
                    af[m], bfr[n], acc[m][n], 0, 0, 0);
        __syncthreads();   // all waves done reading before next overwrite
    }

    // C/D layout: col = lane&15, row = (lane>>4)*4 + j   [m89-verified]
    const int rbase = m0 + wr + ((lane >> 4) << 2);
    const int cbase = n0 + wc + (lane & 15);
    #pragma unroll
    for (int n = 0; n < 4; ++n) {
        const int col = cbase + n * 16;
        const float bv = BIAS ? bias[col] : 0.f;
        #pragma unroll
        for (int m = 0; m < 4; ++m) {
            #pragma unroll
            for (int j = 0; j < 4; ++j) {
                float v = acc[m][n][j] + bv;
                if (ACT == 1) v = softplus_f(v);
                C[(size_t)(rbase + m * 16 + j) * ldc + col] = v;
            }
        }
    }
}

// ---------------------------------------------------------------------------
// fp32 GEMM (kept for x_proj, N=96): C = A @ W^T
// ---------------------------------------------------------------------------
template<int BIAS, int ACT>
__global__ __launch_bounds__(256) void gemm_nt(
    const float* __restrict__ A, int lda,
    const float* __restrict__ W,
    const float* __restrict__ bias,
    float* __restrict__ C, int ldc,
    int M, int N, int K)
{
    __shared__ float As[16][68];
    __shared__ float Ws[16][68];
    const int tid = threadIdx.x;
    const int tx = tid & 15, ty = tid >> 4;
    const int m0 = blockIdx.y * 64, n0 = blockIdx.x * 64;
    const int r  = tid >> 2;
    const int c4 = (tid & 3) << 2;
    const int arow = m0 + r;
    const int wrow = n0 + r;

    float acc[4][4] = {};

    for (int k0 = 0; k0 < K; k0 += 16) {
        float4 av = *(const float4*)&A[(size_t)arow * lda + k0 + c4];
        float4 wv = make_float4(0.f, 0.f, 0.f, 0.f);
        if (wrow < N) wv = *(const float4*)&W[(size_t)wrow * K + k0 + c4];
        As[c4+0][r] = av.x; As[c4+1][r] = av.y; As[c4+2][r] = av.z; As[c4+3][r] = av.w;
        Ws[c4+0][r] = wv.x; Ws[c4+1][r] = wv.y; Ws[c4+2][r] = wv.z; Ws[c4+3][r] = wv.w;
        __syncthreads();
        #pragma unroll
        for (int k = 0; k < 16; ++k) {
            float4 a = *(const float4*)&As[k][ty * 4];
            float4 b = *(const float4*)&Ws[k][tx * 4];
            float ar[4] = {a.x, a.y, a.z, a.w};
            float br[4] = {b.x, b.y, b.z, b.w};
            #pragma unroll
            for (int i = 0; i < 4; ++i)
                #pragma unroll
                for (int j = 0; j < 4; ++j)
                    acc[i][j] = fmaf(ar[i], br[j], acc[i][j]);
        }
        __syncthreads();
    }

    #pragma unroll
    for (int i = 0; i < 4; ++i) {
        const int row = m0 + ty * 4 + i;
        #pragma unroll
        for (int j = 0; j < 4; ++j) {
            const int col = n0 + tx * 4 + j;
            if (col < N) {
                float v = acc[i][j];
                if (BIAS) v += bias[col];
                if (ACT == 1) v = softplus_f(v);
                C[(size_t)row * ldc + col] = v;
            }
        }
    }
}

// ---------------------------------------------------------------------------
// Causal depthwise conv (K=4) + bias + silu.
// ---------------------------------------------------------------------------
__global__ __launch_bounds__(256) void conv_silu_k(
    const float* __restrict__ xr, const float* __restrict__ cw,
    const float* __restrict__ cb, float* __restrict__ xs)
{
    const int idx = blockIdx.x * 256 + threadIdx.x;
    const int l = idx >> 11;
    const int d = idx & (DI - 1);
    float acc = cb[d];
    const float w0 = cw[d*4+0], w1 = cw[d*4+1], w2 = cw[d*4+2], w3 = cw[d*4+3];
    if (l >= 3) acc = fmaf(xr[(size_t)(l-3)*(2*DI) + d], w0, acc);
    if (l >= 2) acc = fmaf(xr[(size_t)(l-2)*(2*DI) + d], w1, acc);
    if (l >= 1) acc = fmaf(xr[(size_t)(l-1)*(2*DI) + d], w2, acc);
    acc = fmaf(xr[(size_t)l*(2*DI) + d], w3, acc);
    xs[idx] = silu_f(acc);
}

// ---------------------------------------------------------------------------
// Scan phase 1: per-(chunk, channel) local scan, h=0 start.
// ---------------------------------------------------------------------------
__global__ __launch_bounds__(256) void scan1_k(
    const float* __restrict__ delta, const float* __restrict__ xs,
    const float* __restrict__ A_log, const float* __restrict__ xdbl,
    float* __restrict__ P, float* __restrict__ S)
{
    const int d = blockIdx.x * 256 + threadIdx.x;
    const int c = blockIdx.y;
    float A[NS];
    #pragma unroll
    for (int n = 0; n < NS; ++n) A[n] = -__expf(A_log[d * NS + n]);
    float h[NS] = {};
    float ap[NS];
    #pragma unroll
    for (int n = 0; n < NS; ++n) ap[n] = 1.f;

    const int l0 = c * CL;
    for (int l = l0; l < l0 + CL; ++l) {
        const float dt = delta[(size_t)l * DI + d];
        const float u  = xs[(size_t)l * DI + d];
        const float du = dt * u;
        #pragma unroll
        for (int n = 0; n < NS; ++n) {
            const float Bn = xdbl[(size_t)l * 96 + RR + n];
            const float dA = __expf(dt * A[n]);
            h[n]  = fmaf(dA, h[n], du * Bn);
            ap[n] *= dA;
        }
    }
    const size_t base = ((size_t)c * DI + d) * NS;
    #pragma unroll
    for (int n = 0; n < NS; ++n) { P[base + n] = ap[n]; S[base + n] = h[n]; }
}

// ---------------------------------------------------------------------------
// Scan phase 2: sequential over NC chunks; exclusive prefix per (d,n).
// ---------------------------------------------------------------------------
__global__ __launch_bounds__(256) void scan2_k(
    const float* __restrict__ P, const float* __restrict__ S, float* __restrict__ Hp)
{
    const int idx = blockIdx.x * 256 + threadIdx.x;
    float h = 0.f;
    for (int c = 0; c < NC; ++c) {
        const size_t o = (size_t)c * DI * NS + idx;
        Hp[o] = h;
        h = fmaf(P[o], h, S[o]);
    }
}

// ---------------------------------------------------------------------------
// Scan phase 3: replay with prefix, y = (h.C + xs*D)*silu(res), write bf16.
// ---------------------------------------------------------------------------
__global__ __launch_bounds__(256) void scan3_k(
    const float* __restrict__ delta, const float* __restrict__ xs,
    const float* __restrict__ A_log, const float* __restrict__ xdbl,
    const float* __restrict__ Hp, const float* __restrict__ xr,
    const float* __restrict__ Dp, __bf16* __restrict__ y_bf)
{
    const int d = blockIdx.x * 256 + threadIdx.x;
    const int c = blockIdx.y;
    float A[NS];
    #pragma unroll
    for (int n = 0; n < NS; ++n) A[n] = -__expf(A_log[d * NS + n]);
    float h[NS];
    const size_t base = ((size_t)c * DI + d) * NS;
    #pragma unroll
    for (int n = 0; n < NS; ++n) h[n] = Hp[base + n];
    const float Dd = Dp[d];

    const int l0 = c * CL;
    for (int l = l0; l < l0 + CL; ++l) {
        const float dt = delta[(size_t)l * DI + d];
        const float u  = xs[(size_t)l * DI + d];
        const float du = dt * u;
        float acc = 0.f;
        #pragma unroll
        for (int n = 0; n < NS; ++n) {
            const float Bn = xdbl[(size_t)l * 96 + RR + n];
            const float Cn = xdbl[(size_t)l * 96 + RR + NS + n];
            const float dA = __expf(dt * A[n]);
            h[n] = fmaf(dA, h[n], du * Bn);
            acc  = fmaf(h[n], Cn, acc);
        }
        float yv = fmaf(u, Dd, acc);
        const float r = xr[(size_t)l * (2*DI) + DI + d];
        yv *= silu_f(r);
        y_bf[(size_t)l * DI + d] = (__bf16)yv;
    }
}

// ---------------------------------------------------------------------------
extern "C" void kernel_launch(void* const* d_in, const int* in_sizes, int n_in,
                              void* d_out, int out_size, void* d_ws, size_t ws_size,
                              hipStream_t stream)
{
    const float* x        = (const float*)d_in[0];   // [L][H]
    const float* in_w     = (const float*)d_in[1];   // [2DI][H]
    const float* in_b     = (const float*)d_in[2];   // [2DI]
    const float* conv_w   = (const float*)d_in[3];   // [DI][1][4]
    const float* conv_b   = (const float*)d_in[4];   // [DI]
    const float* xproj_w  = (const float*)d_in[5];   // [96][DI]
    const float* dtproj_w = (const float*)d_in[6];   // [DI][R]
    const float* dtproj_b = (const float*)d_in[7];   // [DI]
    const float* A_log    = (const float*)d_in[8];   // [DI][N]
    const float* Dp       = (const float*)d_in[9];   // [DI]
    const float* outw     = (const float*)d_in[10];  // [H][DI]
    float* out = (float*)d_out;                      // [L][H]

    // fp32 workspace
    float* ws    = (float*)d_ws;
    float* xr    = ws;                                 // [L][2DI]
    float* xs    = xr    + (size_t)LL * 2 * DI;        // [L][DI]
    float* xdbl  = xs    + (size_t)LL * DI;            // [L][96]
    float* delta = xdbl  + (size_t)LL * 96;            // [L][DI]
    float* P     = delta + (size_t)LL * DI;            // [NC][DI][NS]
    float* S     = P     + (size_t)NC * DI * NS;
    float* Hp    = S     + (size_t)NC * DI * NS;
    // bf16 workspace
    __bf16* x_bf    = (__bf16*)(Hp + (size_t)NC * DI * NS);
    __bf16* inw_bf  = x_bf    + (size_t)LL * H_DIM;       // [2DI][H]
    __bf16* outw_bf = inw_bf  + (size_t)2 * DI * H_DIM;   // [H][DI]
    __bf16* dtw_bf  = outw_bf + (size_t)H_DIM * DI;       // [DI][R]
    __bf16* xdbl_bf = dtw_bf  + (size_t)DI * RR;          // [L][96]
    __bf16* y_bf    = xdbl_bf + (size_t)LL * 96;          // [L][DI]

    const dim3 blk(256);

    // weight / input conversions (independent)
    f2b_k<<<dim3((LL * H_DIM) / 1024), blk, 0, stream>>>(x, x_bf);
    f2b_k<<<dim3((2 * DI * H_DIM) / 1024), blk, 0, stream>>>(in_w, inw_bf);
    f2b_k<<<dim3((H_DIM * DI) / 1024), blk, 0, stream>>>(outw, outw_bf);
    f2b_k<<<dim3((DI * RR) / 1024), blk, 0, stream>>>(dtproj_w, dtw_bf);

    // 1) x_and_res = x @ in_proj_w^T + in_proj_b           [L][2DI] fp32
    gemm_bf16_nt<1,0><<<dim3((2*DI)/128, LL/128), blk, 0, stream>>>(
        x_bf, H_DIM, inw_bf, H_DIM, in_b, xr, 2*DI, H_DIM);

    // 2) xs = silu(conv(xc) + conv_b)                      [L][DI]
    conv_silu_k<<<dim3((LL*DI)/256), blk, 0, stream>>>(xr, conv_w, conv_b, xs);

    // 3) x_dbl = xs @ x_proj_w^T                           [L][96] fp32
    gemm_nt<0,0><<<dim3(2, LL/64), blk, 0, stream>>>(
        xs, DI, xproj_w, nullptr, xdbl, 96, LL, 96, DI);

    // 4) delta = softplus(x_dbl[:, :64] @ dt_proj_w^T + b) [L][DI]
    f2b_k<<<dim3((LL * 96) / 1024), blk, 0, stream>>>(xdbl, xdbl_bf);
    gemm_bf16_nt<1,1><<<dim3(DI/128, LL/128), blk, 0, stream>>>(
        xdbl_bf, 96, dtw_bf, RR, dtproj_b, delta, DI, RR);

    // 5-7) chunked scan; scan3 emits y as bf16
    scan1_k<<<dim3(DI/256, NC), blk, 0, stream>>>(delta, xs, A_log, xdbl, P, S);
    scan2_k<<<dim3((DI*NS)/256), blk, 0, stream>>>(P, S, Hp);
    scan3_k<<<dim3(DI/256, NC), blk, 0, stream>>>(delta, xs, A_log, xdbl, Hp, xr, Dp, y_bf);

    // 8) out = y @ out_proj_w^T                            [L][H]
    gemm_bf16_nt<0,0><<<dim3(H_DIM/128, LL/128), blk, 0, stream>>>(
        y_bf, DI, outw_bf, DI, nullptr, out, H_DIM, DI);
}

// Round 3
// 311.794 us; speedup vs baseline: 2.1801x; 1.2845x over previous
//
#include <hip/hip_runtime.h>
#include <hip/hip_bf16.h>
#include <math.h>

// Mamba forward, B=1, L=2048, H=1024, DI=2048, N=16, R=64, K=4
#define H_DIM 1024
#define DI    2048
#define NS    16
#define RR    64
#define LL    2048
#define NC    32   // chunks for the parallel scan
#define CL    64   // chunk length = LL/NC
#define KSPL  16   // split-K factor for x_proj

typedef __bf16 bf16x8 __attribute__((ext_vector_type(8)));
typedef __bf16 bf16x4 __attribute__((ext_vector_type(4)));
typedef float  f32x4  __attribute__((ext_vector_type(4)));

__device__ __forceinline__ float silu_f(float x)  { return x / (1.f + __expf(-x)); }
__device__ __forceinline__ float softplus_f(float x) {
    return fmaxf(x, 0.f) + log1pf(__expf(-fabsf(x)));
}

__device__ __forceinline__ void gload16(const void* g, void* l) {
    __builtin_amdgcn_global_load_lds(
        (const __attribute__((address_space(1))) void*)g,
        (__attribute__((address_space(3))) void*)l, 16, 0, 0);
}

// ---------------------------------------------------------------------------
// fp32 -> bf16 converter (n multiple of 1024, grid = n/1024)
// ---------------------------------------------------------------------------
__global__ __launch_bounds__(256) void f2b_k(const float* __restrict__ in,
                                             __bf16* __restrict__ out)
{
    const size_t i = ((size_t)blockIdx.x * 256 + threadIdx.x) * 4;
    float4 v = *(const float4*)&in[i];
    bf16x4 o;
    o[0] = (__bf16)v.x; o[1] = (__bf16)v.y; o[2] = (__bf16)v.z; o[3] = (__bf16)v.w;
    *(bf16x4*)&out[i] = o;
}

// x_proj weight [96][2048] -> padded bf16 [128][2048] (rows >=96 zero)
__global__ __launch_bounds__(256) void padw_k(const float* __restrict__ w,
                                              __bf16* __restrict__ wp)
{
    const int idx = (blockIdx.x * 256 + threadIdx.x) * 4;   // over 128*2048
    const int row = idx >> 11;
    float4 v = make_float4(0.f, 0.f, 0.f, 0.f);
    if (row < 96) v = *(const float4*)&w[(size_t)row * 2048 + (idx & 2047)];
    bf16x4 o;
    o[0] = (__bf16)v.x; o[1] = (__bf16)v.y; o[2] = (__bf16)v.z; o[3] = (__bf16)v.w;
    *(bf16x4*)&wp[idx] = o;
}

// sum the KSPL split-K partials of x_dbl; emit fp32 + bf16
__global__ __launch_bounds__(256) void reduce_xdbl_k(
    const float* __restrict__ part, float* __restrict__ xdbl,
    __bf16* __restrict__ xdbl_bf)
{
    const int idx = blockIdx.x * 256 + threadIdx.x;   // over LL*96
    float s = 0.f;
    #pragma unroll
    for (int z = 0; z < KSPL; ++z) s += part[(size_t)z * (LL * 96) + idx];
    xdbl[idx] = s;
    xdbl_bf[idx] = (__bf16)s;
}

// ---------------------------------------------------------------------------
// bf16 MFMA GEMM: C = A[M,K] @ W[N,K]^T (+bias)(+softplus), fp32 out.
// 128x128 tile, 4 waves, 4x4 frags of 16x16x32, BK=32, global_load_lds w16.
// grid = (ntiles, mtiles, SPLITK). ncols guards the C write (W rows padded).
// ---------------------------------------------------------------------------
template<int BIAS, int ACT, int SPLITK>
__global__ __launch_bounds__(256) void gemm_bf16_nt(
    const __bf16* __restrict__ A, int lda,
    const __bf16* __restrict__ W, int ldw,
    const float* __restrict__ bias,
    float* __restrict__ C, int ldc, int ncols, size_t pstride,
    int K)
{
    __shared__ __bf16 smA[128 * 32];
    __shared__ __bf16 smB[128 * 32];
    const int t    = threadIdx.x;
    const int lane = t & 63;
    const int m0 = blockIdx.y * 128, n0 = blockIdx.x * 128;
    const int wr = ((t >> 6) >> 1) * 64;        // wave row offset (0/64)
    const int wc = ((t >> 6) & 1) * 64;         // wave col offset (0/64)

    const int srow = t >> 2;                    // 0..63
    const int skof = (t & 3) * 8;               // 0/8/16/24
    const int lds_base = (t >> 6) * 512;        // elements (wave-uniform)

    const int offA = (wr + (lane & 15)) * 32 + ((lane >> 4) * 8);
    const int offB = (wc + (lane & 15)) * 32 + ((lane >> 4) * 8);

    const int kseg  = K / SPLITK;
    const int kbase = (SPLITK > 1) ? blockIdx.z * kseg : 0;

    f32x4 acc[4][4] = {};

    for (int k0 = kbase; k0 < kbase + kseg; k0 += 32) {
        gload16(A + (size_t)(m0 + srow)      * lda + k0 + skof, &smA[lds_base]);
        gload16(A + (size_t)(m0 + 64 + srow) * lda + k0 + skof, &smA[2048 + lds_base]);
        gload16(W + (size_t)(n0 + srow)      * ldw + k0 + skof, &smB[lds_base]);
        gload16(W + (size_t)(n0 + 64 + srow) * ldw + k0 + skof, &smB[2048 + lds_base]);
        __syncthreads();   // drains vmcnt -> LDS tiles ready

        bf16x8 af[4], bfr[4];
        #pragma unroll
        for (int m = 0; m < 4; ++m) af[m]  = *(const bf16x8*)&smA[offA + m * 512];
        #pragma unroll
        for (int n = 0; n < 4; ++n) bfr[n] = *(const bf16x8*)&smB[offB + n * 512];
        #pragma unroll
        for (int m = 0; m < 4; ++m)
            #pragma unroll
            for (int n = 0; n < 4; ++n)
                acc[m][n] = __builtin_amdgcn_mfma_f32_16x16x32_bf16(
                    af[m], bfr[n], acc[m][n], 0, 0, 0);
        __syncthreads();
    }

    float* Cp = C + ((SPLITK > 1) ? (size_t)blockIdx.z * pstride : 0);
    // C/D layout: col = lane&15, row = (lane>>4)*4 + j
    const int rbase = m0 + wr + ((lane >> 4) << 2);
    const int cbase = n0 + wc + (lane & 15);
    #pragma unroll
    for (int n = 0; n < 4; ++n) {
        const int col = cbase + n * 16;
        if (col >= ncols) continue;
        const float bv = BIAS ? bias[col] : 0.f;
        #pragma unroll
        for (int m = 0; m < 4; ++m) {
            #pragma unroll
            for (int j = 0; j < 4; ++j) {
                float v = acc[m][n][j] + bv;
                if (ACT == 1) v = softplus_f(v);
                Cp[(size_t)(rbase + m * 16 + j) * ldc + col] = v;
            }
        }
    }
}

// ---------------------------------------------------------------------------
// Causal depthwise conv (K=4) + bias + silu; emits fp32 and bf16.
// ---------------------------------------------------------------------------
__global__ __launch_bounds__(256) void conv_silu_k(
    const float* __restrict__ xr, const float* __restrict__ cw,
    const float* __restrict__ cb, float* __restrict__ xs,
    __bf16* __restrict__ xs_bf)
{
    const int idx = blockIdx.x * 256 + threadIdx.x;
    const int l = idx >> 11;
    const int d = idx & (DI - 1);
    float acc = cb[d];
    const float w0 = cw[d*4+0], w1 = cw[d*4+1], w2 = cw[d*4+2], w3 = cw[d*4+3];
    if (l >= 3) acc = fmaf(xr[(size_t)(l-3)*(2*DI) + d], w0, acc);
    if (l >= 2) acc = fmaf(xr[(size_t)(l-2)*(2*DI) + d], w1, acc);
    if (l >= 1) acc = fmaf(xr[(size_t)(l-1)*(2*DI) + d], w2, acc);
    acc = fmaf(xr[(size_t)l*(2*DI) + d], w3, acc);
    const float s = silu_f(acc);
    xs[idx] = s;
    xs_bf[idx] = (__bf16)s;
}

// ---------------------------------------------------------------------------
// Scan phase 1: per-(chunk, channel) local scan, h=0 start.
// ---------------------------------------------------------------------------
__global__ __launch_bounds__(256) void scan1_k(
    const float* __restrict__ delta, const float* __restrict__ xs,
    const float* __restrict__ A_log, const float* __restrict__ xdbl,
    float* __restrict__ P, float* __restrict__ S)
{
    const int d = blockIdx.x * 256 + threadIdx.x;
    const int c = blockIdx.y;
    float A[NS];
    #pragma unroll
    for (int n = 0; n < NS; ++n) A[n] = -__expf(A_log[d * NS + n]);
    float h[NS] = {};
    float ap[NS];
    #pragma unroll
    for (int n = 0; n < NS; ++n) ap[n] = 1.f;

    const int l0 = c * CL;
    for (int l = l0; l < l0 + CL; ++l) {
        const float dt = delta[(size_t)l * DI + d];
        const float u  = xs[(size_t)l * DI + d];
        const float du = dt * u;
        #pragma unroll
        for (int n = 0; n < NS; ++n) {
            const float Bn = xdbl[(size_t)l * 96 + RR + n];
            const float dA = __expf(dt * A[n]);
            h[n]  = fmaf(dA, h[n], du * Bn);
            ap[n] *= dA;
        }
    }
    const size_t base = ((size_t)c * DI + d) * NS;
    #pragma unroll
    for (int n = 0; n < NS; ++n) { P[base + n] = ap[n]; S[base + n] = h[n]; }
}

// ---------------------------------------------------------------------------
// Scan phase 2: sequential over NC chunks; exclusive prefix per (d,n).
// ---------------------------------------------------------------------------
__global__ __launch_bounds__(256) void scan2_k(
    const float* __restrict__ P, const float* __restrict__ S, float* __restrict__ Hp)
{
    const int idx = blockIdx.x * 256 + threadIdx.x;
    float h = 0.f;
    for (int c = 0; c < NC; ++c) {
        const size_t o = (size_t)c * DI * NS + idx;
        Hp[o] = h;
        h = fmaf(P[o], h, S[o]);
    }
}

// ---------------------------------------------------------------------------
// Scan phase 3: replay with prefix, y = (h.C + xs*D)*silu(res), write bf16.
// ---------------------------------------------------------------------------
__global__ __launch_bounds__(256) void scan3_k(
    const float* __restrict__ delta, const float* __restrict__ xs,
    const float* __restrict__ A_log, const float* __restrict__ xdbl,
    const float* __restrict__ Hp, const float* __restrict__ xr,
    const float* __restrict__ Dp, __bf16* __restrict__ y_bf)
{
    const int d = blockIdx.x * 256 + threadIdx.x;
    const int c = blockIdx.y;
    float A[NS];
    #pragma unroll
    for (int n = 0; n < NS; ++n) A[n] = -__expf(A_log[d * NS + n]);
    float h[NS];
    const size_t base = ((size_t)c * DI + d) * NS;
    #pragma unroll
    for (int n = 0; n < NS; ++n) h[n] = Hp[base + n];
    const float Dd = Dp[d];

    const int l0 = c * CL;
    for (int l = l0; l < l0 + CL; ++l) {
        const float dt = delta[(size_t)l * DI + d];
        const float u  = xs[(size_t)l * DI + d];
        const float du = dt * u;
        float acc = 0.f;
        #pragma unroll
        for (int n = 0; n < NS; ++n) {
            const float Bn = xdbl[(size_t)l * 96 + RR + n];
            const float Cn = xdbl[(size_t)l * 96 + RR + NS + n];
            const float dA = __expf(dt * A[n]);
            h[n] = fmaf(dA, h[n], du * Bn);
            acc  = fmaf(h[n], Cn, acc);
        }
        float yv = fmaf(u, Dd, acc);
        const float r = xr[(size_t)l * (2*DI) + DI + d];
        yv *= silu_f(r);
        y_bf[(size_t)l * DI + d] = (__bf16)yv;
    }
}

// ---------------------------------------------------------------------------
extern "C" void kernel_launch(void* const* d_in, const int* in_sizes, int n_in,
                              void* d_out, int out_size, void* d_ws, size_t ws_size,
                              hipStream_t stream)
{
    const float* x        = (const float*)d_in[0];   // [L][H]
    const float* in_w     = (const float*)d_in[1];   // [2DI][H]
    const float* in_b     = (const float*)d_in[2];   // [2DI]
    const float* conv_w   = (const float*)d_in[3];   // [DI][1][4]
    const float* conv_b   = (const float*)d_in[4];   // [DI]
    const float* xproj_w  = (const float*)d_in[5];   // [96][DI]
    const float* dtproj_w = (const float*)d_in[6];   // [DI][R]
    const float* dtproj_b = (const float*)d_in[7];   // [DI]
    const float* A_log    = (const float*)d_in[8];   // [DI][N]
    const float* Dp       = (const float*)d_in[9];   // [DI]
    const float* outw     = (const float*)d_in[10];  // [H][DI]
    float* out = (float*)d_out;                      // [L][H]

    // fp32 workspace
    float* ws    = (float*)d_ws;
    float* xr    = ws;                                 // [L][2DI]
    float* xs    = xr    + (size_t)LL * 2 * DI;        // [L][DI]
    float* xdbl  = xs    + (size_t)LL * DI;            // [L][96]
    float* delta = xdbl  + (size_t)LL * 96;            // [L][DI]  (split-K partials alias here)
    float* P     = delta + (size_t)LL * DI;            // [NC][DI][NS]
    float* S     = P     + (size_t)NC * DI * NS;
    float* Hp    = S     + (size_t)NC * DI * NS;
    float* xpart = delta;                              // [KSPL][L][96] (12.6MB < 16MB, consumed before delta written)
    // bf16 workspace
    __bf16* x_bf    = (__bf16*)(Hp + (size_t)NC * DI * NS);
    __bf16* inw_bf  = x_bf    + (size_t)LL * H_DIM;       // [2DI][H]
    __bf16* outw_bf = inw_bf  + (size_t)2 * DI * H_DIM;   // [H][DI]
    __bf16* dtw_bf  = outw_bf + (size_t)H_DIM * DI;       // [DI][R]
    __bf16* xdbl_bf = dtw_bf  + (size_t)DI * RR;          // [L][96]
    __bf16* y_bf    = xdbl_bf + (size_t)LL * 96;          // [L][DI]
    __bf16* xs_bf   = y_bf    + (size_t)LL * DI;          // [L][DI]
    __bf16* xpw_pad = xs_bf   + (size_t)LL * DI;          // [128][DI]

    const dim3 blk(256);

    // weight / input conversions (independent)
    f2b_k<<<dim3((LL * H_DIM) / 1024), blk, 0, stream>>>(x, x_bf);
    f2b_k<<<dim3((2 * DI * H_DIM) / 1024), blk, 0, stream>>>(in_w, inw_bf);
    f2b_k<<<dim3((H_DIM * DI) / 1024), blk, 0, stream>>>(outw, outw_bf);
    f2b_k<<<dim3((DI * RR) / 1024), blk, 0, stream>>>(dtproj_w, dtw_bf);
    padw_k<<<dim3((128 * DI) / 1024), blk, 0, stream>>>(xproj_w, xpw_pad);

    // 1) x_and_res = x @ in_proj_w^T + in_proj_b           [L][2DI] fp32
    gemm_bf16_nt<1,0,1><<<dim3((2*DI)/128, LL/128), blk, 0, stream>>>(
        x_bf, H_DIM, inw_bf, H_DIM, in_b, xr, 2*DI, 2*DI, 0, H_DIM);

    // 2) xs = silu(conv(xc) + conv_b)                      [L][DI] fp32+bf16
    conv_silu_k<<<dim3((LL*DI)/256), blk, 0, stream>>>(xr, conv_w, conv_b, xs, xs_bf);

    // 3) x_dbl = xs @ x_proj_w^T  (split-K MFMA + reduce)  [L][96] fp32+bf16
    gemm_bf16_nt<0,0,KSPL><<<dim3(1, LL/128, KSPL), blk, 0, stream>>>(
        xs_bf, DI, xpw_pad, DI, nullptr, xpart, 96, 96, (size_t)LL * 96, DI);
    reduce_xdbl_k<<<dim3((LL * 96) / 256), blk, 0, stream>>>(xpart, xdbl, xdbl_bf);

    // 4) delta = softplus(x_dbl[:, :64] @ dt_proj_w^T + b) [L][DI]
    gemm_bf16_nt<1,1,1><<<dim3(DI/128, LL/128), blk, 0, stream>>>(
        xdbl_bf, 96, dtw_bf, RR, dtproj_b, delta, DI, DI, 0, RR);

    // 5-7) chunked scan; scan3 emits y as bf16
    scan1_k<<<dim3(DI/256, NC), blk, 0, stream>>>(delta, xs, A_log, xdbl, P, S);
    scan2_k<<<dim3((DI*NS)/256), blk, 0, stream>>>(P, S, Hp);
    scan3_k<<<dim3(DI/256, NC), blk, 0, stream>>>(delta, xs, A_log, xdbl, Hp, xr, Dp, y_bf);

    // 8) out = y @ out_proj_w^T                            [L][H]
    gemm_bf16_nt<0,0,1><<<dim3(H_DIM/128, LL/128), blk, 0, stream>>>(
        y_bf, DI, outw_bf, DI, nullptr, out, H_DIM, H_DIM, 0, DI);
}

// Round 4
// 294.549 us; speedup vs baseline: 2.3078x; 1.0585x over previous
//
#include <hip/hip_runtime.h>
#include <hip/hip_bf16.h>
#include <math.h>

// Mamba forward, B=1, L=2048, H=1024, DI=2048, N=16, R=64, K=4
#define H_DIM 1024
#define DI    2048
#define NS    16
#define RR    64
#define LL    2048
#define NC    32   // chunks for the parallel scan
#define CL    64   // chunk length = LL/NC
#define KSPL  16   // split-K factor for x_proj

typedef __bf16 bf16x8 __attribute__((ext_vector_type(8)));
typedef __bf16 bf16x4 __attribute__((ext_vector_type(4)));
typedef float  f32x4  __attribute__((ext_vector_type(4)));

__device__ __forceinline__ float silu_f(float x)  { return x / (1.f + __expf(-x)); }
// Cheap softplus: hw exp/log only. |err| < 3e-7 at crossover; x>15 -> x exact
// to fp32. (log1pf forced a libm slow path: VGPR=84 w/ acc spills, 97us epilogue.)
__device__ __forceinline__ float softplus_f(float x) {
    const float l = __logf(1.f + __expf(x));
    return x > 15.f ? x : l;
}

__device__ __forceinline__ void gload16(const void* g, void* l) {
    __builtin_amdgcn_global_load_lds(
        (const __attribute__((address_space(1))) void*)g,
        (__attribute__((address_space(3))) void*)l, 16, 0, 0);
}

// ---------------------------------------------------------------------------
// fp32 -> bf16 converter (n multiple of 1024, grid = n/1024)
// ---------------------------------------------------------------------------
__global__ __launch_bounds__(256) void f2b_k(const float* __restrict__ in,
                                             __bf16* __restrict__ out)
{
    const size_t i = ((size_t)blockIdx.x * 256 + threadIdx.x) * 4;
    float4 v = *(const float4*)&in[i];
    bf16x4 o;
    o[0] = (__bf16)v.x; o[1] = (__bf16)v.y; o[2] = (__bf16)v.z; o[3] = (__bf16)v.w;
    *(bf16x4*)&out[i] = o;
}

// x_proj weight [96][2048] -> padded bf16 [128][2048] (rows >=96 zero)
__global__ __launch_bounds__(256) void padw_k(const float* __restrict__ w,
                                              __bf16* __restrict__ wp)
{
    const int idx = (blockIdx.x * 256 + threadIdx.x) * 4;   // over 128*2048
    const int row = idx >> 11;
    float4 v = make_float4(0.f, 0.f, 0.f, 0.f);
    if (row < 96) v = *(const float4*)&w[(size_t)row * 2048 + (idx & 2047)];
    bf16x4 o;
    o[0] = (__bf16)v.x; o[1] = (__bf16)v.y; o[2] = (__bf16)v.z; o[3] = (__bf16)v.w;
    *(bf16x4*)&wp[idx] = o;
}

// sum the KSPL split-K partials of x_dbl; emit fp32 + bf16
__global__ __launch_bounds__(256) void reduce_xdbl_k(
    const float* __restrict__ part, float* __restrict__ xdbl,
    __bf16* __restrict__ xdbl_bf)
{
    const int idx = blockIdx.x * 256 + threadIdx.x;   // over LL*96
    float s = 0.f;
    #pragma unroll
    for (int z = 0; z < KSPL; ++z) s += part[(size_t)z * (LL * 96) + idx];
    xdbl[idx] = s;
    xdbl_bf[idx] = (__bf16)s;
}

// ---------------------------------------------------------------------------
// bf16 MFMA GEMM: C = A[M,K] @ W[N,K]^T (+bias)(+softplus), fp32 out.
// 128x128 tile, 4 waves, 4x4 frags of 16x16x32, BK=32, global_load_lds w16.
// grid = (ntiles, mtiles, SPLITK). ncols guards the C write (W rows padded).
// ---------------------------------------------------------------------------
template<int BIAS, int ACT, int SPLITK>
__global__ __launch_bounds__(256) void gemm_bf16_nt(
    const __bf16* __restrict__ A, int lda,
    const __bf16* __restrict__ W, int ldw,
    const float* __restrict__ bias,
    float* __restrict__ C, int ldc, int ncols, size_t pstride,
    int K)
{
    __shared__ __bf16 smA[128 * 32];
    __shared__ __bf16 smB[128 * 32];
    const int t    = threadIdx.x;
    const int lane = t & 63;
    const int m0 = blockIdx.y * 128, n0 = blockIdx.x * 128;
    const int wr = ((t >> 6) >> 1) * 64;        // wave row offset (0/64)
    const int wc = ((t >> 6) & 1) * 64;         // wave col offset (0/64)

    const int srow = t >> 2;                    // 0..63
    const int skof = (t & 3) * 8;               // 0/8/16/24
    const int lds_base = (t >> 6) * 512;        // elements (wave-uniform)

    const int offA = (wr + (lane & 15)) * 32 + ((lane >> 4) * 8);
    const int offB = (wc + (lane & 15)) * 32 + ((lane >> 4) * 8);

    const int kseg  = K / SPLITK;
    const int kbase = (SPLITK > 1) ? blockIdx.z * kseg : 0;

    f32x4 acc[4][4] = {};

    for (int k0 = kbase; k0 < kbase + kseg; k0 += 32) {
        gload16(A + (size_t)(m0 + srow)      * lda + k0 + skof, &smA[lds_base]);
        gload16(A + (size_t)(m0 + 64 + srow) * lda + k0 + skof, &smA[2048 + lds_base]);
        gload16(W + (size_t)(n0 + srow)      * ldw + k0 + skof, &smB[lds_base]);
        gload16(W + (size_t)(n0 + 64 + srow) * ldw + k0 + skof, &smB[2048 + lds_base]);
        __syncthreads();   // drains vmcnt -> LDS tiles ready

        bf16x8 af[4], bfr[4];
        #pragma unroll
        for (int m = 0; m < 4; ++m) af[m]  = *(const bf16x8*)&smA[offA + m * 512];
        #pragma unroll
        for (int n = 0; n < 4; ++n) bfr[n] = *(const bf16x8*)&smB[offB + n * 512];
        #pragma unroll
        for (int m = 0; m < 4; ++m)
            #pragma unroll
            for (int n = 0; n < 4; ++n)
                acc[m][n] = __builtin_amdgcn_mfma_f32_16x16x32_bf16(
                    af[m], bfr[n], acc[m][n], 0, 0, 0);
        __syncthreads();
    }

    float* Cp = C + ((SPLITK > 1) ? (size_t)blockIdx.z * pstride : 0);
    // C/D layout: col = lane&15, row = (lane>>4)*4 + j
    const int rbase = m0 + wr + ((lane >> 4) << 2);
    const int cbase = n0 + wc + (lane & 15);
    #pragma unroll
    for (int n = 0; n < 4; ++n) {
        const int col = cbase + n * 16;
        if (col >= ncols) continue;
        const float bv = BIAS ? bias[col] : 0.f;
        #pragma unroll
        for (int m = 0; m < 4; ++m) {
            #pragma unroll
            for (int j = 0; j < 4; ++j) {
                float v = acc[m][n][j] + bv;
                if (ACT == 1) v = softplus_f(v);
                Cp[(size_t)(rbase + m * 16 + j) * ldc + col] = v;
            }
        }
    }
}

// ---------------------------------------------------------------------------
// Causal depthwise conv (K=4) + bias + silu; emits fp32 and bf16.
// ---------------------------------------------------------------------------
__global__ __launch_bounds__(256) void conv_silu_k(
    const float* __restrict__ xr, const float* __restrict__ cw,
    const float* __restrict__ cb, float* __restrict__ xs,
    __bf16* __restrict__ xs_bf)
{
    const int idx = blockIdx.x * 256 + threadIdx.x;
    const int l = idx >> 11;
    const int d = idx & (DI - 1);
    float acc = cb[d];
    const float w0 = cw[d*4+0], w1 = cw[d*4+1], w2 = cw[d*4+2], w3 = cw[d*4+3];
    if (l >= 3) acc = fmaf(xr[(size_t)(l-3)*(2*DI) + d], w0, acc);
    if (l >= 2) acc = fmaf(xr[(size_t)(l-2)*(2*DI) + d], w1, acc);
    if (l >= 1) acc = fmaf(xr[(size_t)(l-1)*(2*DI) + d], w2, acc);
    acc = fmaf(xr[(size_t)l*(2*DI) + d], w3, acc);
    const float s = silu_f(acc);
    xs[idx] = s;
    xs_bf[idx] = (__bf16)s;
}

// ---------------------------------------------------------------------------
// Scan phase 1: per-(chunk, channel) local scan, h=0 start.
// ---------------------------------------------------------------------------
__global__ __launch_bounds__(256) void scan1_k(
    const float* __restrict__ delta, const float* __restrict__ xs,
    const float* __restrict__ A_log, const float* __restrict__ xdbl,
    float* __restrict__ P, float* __restrict__ S)
{
    const int d = blockIdx.x * 256 + threadIdx.x;
    const int c = blockIdx.y;
    float A[NS];
    #pragma unroll
    for (int n = 0; n < NS; ++n) A[n] = -__expf(A_log[d * NS + n]);
    float h[NS] = {};
    float ap[NS];
    #pragma unroll
    for (int n = 0; n < NS; ++n) ap[n] = 1.f;

    const int l0 = c * CL;
    for (int l = l0; l < l0 + CL; ++l) {
        const float dt = delta[(size_t)l * DI + d];
        const float u  = xs[(size_t)l * DI + d];
        const float du = dt * u;
        #pragma unroll
        for (int n = 0; n < NS; ++n) {
            const float Bn = xdbl[(size_t)l * 96 + RR + n];
            const float dA = __expf(dt * A[n]);
            h[n]  = fmaf(dA, h[n], du * Bn);
            ap[n] *= dA;
        }
    }
    const size_t base = ((size_t)c * DI + d) * NS;
    #pragma unroll
    for (int n = 0; n < NS; ++n) { P[base + n] = ap[n]; S[base + n] = h[n]; }
}

// ---------------------------------------------------------------------------
// Scan phase 2: sequential over NC chunks; exclusive prefix per (d,n).
// ---------------------------------------------------------------------------
__global__ __launch_bounds__(256) void scan2_k(
    const float* __restrict__ P, const float* __restrict__ S, float* __restrict__ Hp)
{
    const int idx = blockIdx.x * 256 + threadIdx.x;
    float h = 0.f;
    for (int c = 0; c < NC; ++c) {
        const size_t o = (size_t)c * DI * NS + idx;
        Hp[o] = h;
        h = fmaf(P[o], h, S[o]);
    }
}

// ---------------------------------------------------------------------------
// Scan phase 3: replay with prefix, y = (h.C + xs*D)*silu(res), write bf16.
// ---------------------------------------------------------------------------
__global__ __launch_bounds__(256) void scan3_k(
    const float* __restrict__ delta, const float* __restrict__ xs,
    const float* __restrict__ A_log, const float* __restrict__ xdbl,
    const float* __restrict__ Hp, const float* __restrict__ xr,
    const float* __restrict__ Dp, __bf16* __restrict__ y_bf)
{
    const int d = blockIdx.x * 256 + threadIdx.x;
    const int c = blockIdx.y;
    float A[NS];
    #pragma unroll
    for (int n = 0; n < NS; ++n) A[n] = -__expf(A_log[d * NS + n]);
    float h[NS];
    const size_t base = ((size_t)c * DI + d) * NS;
    #pragma unroll
    for (int n = 0; n < NS; ++n) h[n] = Hp[base + n];
    const float Dd = Dp[d];

    const int l0 = c * CL;
    for (int l = l0; l < l0 + CL; ++l) {
        const float dt = delta[(size_t)l * DI + d];
        const float u  = xs[(size_t)l * DI + d];
        const float du = dt * u;
        float acc = 0.f;
        #pragma unroll
        for (int n = 0; n < NS; ++n) {
            const float Bn = xdbl[(size_t)l * 96 + RR + n];
            const float Cn = xdbl[(size_t)l * 96 + RR + NS + n];
            const float dA = __expf(dt * A[n]);
            h[n] = fmaf(dA, h[n], du * Bn);
            acc  = fmaf(h[n], Cn, acc);
        }
        float yv = fmaf(u, Dd, acc);
        const float r = xr[(size_t)l * (2*DI) + DI + d];
        yv *= silu_f(r);
        y_bf[(size_t)l * DI + d] = (__bf16)yv;
    }
}

// ---------------------------------------------------------------------------
extern "C" void kernel_launch(void* const* d_in, const int* in_sizes, int n_in,
                              void* d_out, int out_size, void* d_ws, size_t ws_size,
                              hipStream_t stream)
{
    const float* x        = (const float*)d_in[0];   // [L][H]
    const float* in_w     = (const float*)d_in[1];   // [2DI][H]
    const float* in_b     = (const float*)d_in[2];   // [2DI]
    const float* conv_w   = (const float*)d_in[3];   // [DI][1][4]
    const float* conv_b   = (const float*)d_in[4];   // [DI]
    const float* xproj_w  = (const float*)d_in[5];   // [96][DI]
    const float* dtproj_w = (const float*)d_in[6];   // [DI][R]
    const float* dtproj_b = (const float*)d_in[7];   // [DI]
    const float* A_log    = (const float*)d_in[8];   // [DI][N]
    const float* Dp       = (const float*)d_in[9];   // [DI]
    const float* outw     = (const float*)d_in[10];  // [H][DI]
    float* out = (float*)d_out;                      // [L][H]

    // fp32 workspace
    float* ws    = (float*)d_ws;
    float* xr    = ws;                                 // [L][2DI]
    float* xs    = xr    + (size_t)LL * 2 * DI;        // [L][DI]
    float* xdbl  = xs    + (size_t)LL * DI;            // [L][96]
    float* delta = xdbl  + (size_t)LL * 96;            // [L][DI]  (split-K partials alias here)
    float* P     = delta + (size_t)LL * DI;            // [NC][DI][NS]
    float* S     = P     + (size_t)NC * DI * NS;
    float* Hp    = S     + (size_t)NC * DI * NS;
    float* xpart = delta;                              // [KSPL][L][96] (12.6MB, consumed before delta written)
    // bf16 workspace
    __bf16* x_bf    = (__bf16*)(Hp + (size_t)NC * DI * NS);
    __bf16* inw_bf  = x_bf    + (size_t)LL * H_DIM;       // [2DI][H]
    __bf16* outw_bf = inw_bf  + (size_t)2 * DI * H_DIM;   // [H][DI]
    __bf16* dtw_bf  = outw_bf + (size_t)H_DIM * DI;       // [DI][R]
    __bf16* xdbl_bf = dtw_bf  + (size_t)DI * RR;          // [L][96]
    __bf16* y_bf    = xdbl_bf + (size_t)LL * 96;          // [L][DI]
    __bf16* xs_bf   = y_bf    + (size_t)LL * DI;          // [L][DI]
    __bf16* xpw_pad = xs_bf   + (size_t)LL * DI;          // [128][DI]

    const dim3 blk(256);

    // weight / input conversions (independent)
    f2b_k<<<dim3((LL * H_DIM) / 1024), blk, 0, stream>>>(x, x_bf);
    f2b_k<<<dim3((2 * DI * H_DIM) / 1024), blk, 0, stream>>>(in_w, inw_bf);
    f2b_k<<<dim3((H_DIM * DI) / 1024), blk, 0, stream>>>(outw, outw_bf);
    f2b_k<<<dim3((DI * RR) / 1024), blk, 0, stream>>>(dtproj_w, dtw_bf);
    padw_k<<<dim3((128 * DI) / 1024), blk, 0, stream>>>(xproj_w, xpw_pad);

    // 1) x_and_res = x @ in_proj_w^T + in_proj_b           [L][2DI] fp32
    gemm_bf16_nt<1,0,1><<<dim3((2*DI)/128, LL/128), blk, 0, stream>>>(
        x_bf, H_DIM, inw_bf, H_DIM, in_b, xr, 2*DI, 2*DI, 0, H_DIM);

    // 2) xs = silu(conv(xc) + conv_b)                      [L][DI] fp32+bf16
    conv_silu_k<<<dim3((LL*DI)/256), blk, 0, stream>>>(xr, conv_w, conv_b, xs, xs_bf);

    // 3) x_dbl = xs @ x_proj_w^T  (split-K MFMA + reduce)  [L][96] fp32+bf16
    gemm_bf16_nt<0,0,KSPL><<<dim3(1, LL/128, KSPL), blk, 0, stream>>>(
        xs_bf, DI, xpw_pad, DI, nullptr, xpart, 96, 96, (size_t)LL * 96, DI);
    reduce_xdbl_k<<<dim3((LL * 96) / 256), blk, 0, stream>>>(xpart, xdbl, xdbl_bf);

    // 4) delta = softplus(x_dbl[:, :64] @ dt_proj_w^T + b) [L][DI]
    gemm_bf16_nt<1,1,1><<<dim3(DI/128, LL/128), blk, 0, stream>>>(
        xdbl_bf, 96, dtw_bf, RR, dtproj_b, delta, DI, DI, 0, RR);

    // 5-7) chunked scan; scan3 emits y as bf16
    scan1_k<<<dim3(DI/256, NC), blk, 0, stream>>>(delta, xs, A_log, xdbl, P, S);
    scan2_k<<<dim3((DI*NS)/256), blk, 0, stream>>>(P, S, Hp);
    scan3_k<<<dim3(DI/256, NC), blk, 0, stream>>>(delta, xs, A_log, xdbl, Hp, xr, Dp, y_bf);

    // 8) out = y @ out_proj_w^T                            [L][H]
    gemm_bf16_nt<0,0,1><<<dim3(H_DIM/128, LL/128), blk, 0, stream>>>(
        y_bf, DI, outw_bf, DI, nullptr, out, H_DIM, H_DIM, 0, DI);
}

// Round 5
// 273.434 us; speedup vs baseline: 2.4860x; 1.0772x over previous
//
#include <hip/hip_runtime.h>
#include <hip/hip_bf16.h>
#include <math.h>

// Mamba forward, B=1, L=2048, H=1024, DI=2048, N=16, R=64, K=4
#define H_DIM 1024
#define DI    2048
#define NS    16
#define RR    64
#define LL    2048
#define NC    32   // chunks for the parallel scan
#define CL    64   // chunk length = LL/NC
#define KSPL  16   // split-K factor for x_proj

typedef __bf16 bf16x8 __attribute__((ext_vector_type(8)));
typedef __bf16 bf16x4 __attribute__((ext_vector_type(4)));
typedef float  f32x4  __attribute__((ext_vector_type(4)));

__device__ __forceinline__ float silu_f(float x)  { return x / (1.f + __expf(-x)); }
// Cheap softplus: hw exp/log only (log1pf libm slow path caused acc spills).
__device__ __forceinline__ float softplus_f(float x) {
    const float l = __logf(1.f + __expf(x));
    return x > 15.f ? x : l;
}

__device__ __forceinline__ void gload16(const void* g, void* l) {
    __builtin_amdgcn_global_load_lds(
        (const __attribute__((address_space(1))) void*)g,
        (__attribute__((address_space(3))) void*)l, 16, 0, 0);
}

__device__ __forceinline__ void f2b4(const float* __restrict__ in,
                                     __bf16* __restrict__ out)
{
    float4 v = *(const float4*)in;
    bf16x4 o;
    o[0] = (__bf16)v.x; o[1] = (__bf16)v.y; o[2] = (__bf16)v.z; o[3] = (__bf16)v.w;
    *(bf16x4*)out = o;
}

// ---------------------------------------------------------------------------
// One fused conversion kernel: x, in_w, outw, dtw (f2b) + x_proj_w pad (f2b,
// rows >=96 zeroed). Segment sizes are compile-time constants.
// ---------------------------------------------------------------------------
#define SEG0 (LL * H_DIM)          // x          2,097,152
#define SEG1 (2 * DI * H_DIM)      // in_w       4,194,304
#define SEG2 (H_DIM * DI)          // outw       2,097,152
#define SEG3 (DI * RR)             // dtw          131,072
#define SEG4 (128 * DI)            // xpw_pad      262,144
#define CUM0 SEG0
#define CUM1 (CUM0 + SEG1)
#define CUM2 (CUM1 + SEG2)
#define CUM3 (CUM2 + SEG3)
#define CUMT (CUM3 + SEG4)         // 8,781,824 elems (/4 = 2,195,456 threads)

__global__ __launch_bounds__(256) void convert_all_k(
    const float* __restrict__ x,    const float* __restrict__ in_w,
    const float* __restrict__ outw, const float* __restrict__ dtw,
    const float* __restrict__ xpw,
    __bf16* __restrict__ x_bf,    __bf16* __restrict__ inw_bf,
    __bf16* __restrict__ outw_bf, __bf16* __restrict__ dtw_bf,
    __bf16* __restrict__ xpw_pad)
{
    const int i = (blockIdx.x * 256 + threadIdx.x) * 4;
    if (i < CUM0) {
        f2b4(x + i, x_bf + i);
    } else if (i < CUM1) {
        const int o = i - CUM0;  f2b4(in_w + o, inw_bf + o);
    } else if (i < CUM2) {
        const int o = i - CUM1;  f2b4(outw + o, outw_bf + o);
    } else if (i < CUM3) {
        const int o = i - CUM2;  f2b4(dtw + o, dtw_bf + o);
    } else if (i < CUMT) {
        const int o = i - CUM3;           // over [128][2048]
        const int row = o >> 11;
        if (row < 96) {
            f2b4(xpw + o, xpw_pad + o);
        } else {
            bf16x4 z; z[0] = z[1] = z[2] = z[3] = (__bf16)0.f;
            *(bf16x4*)&xpw_pad[o] = z;
        }
    }
}

// sum the KSPL split-K partials of x_dbl; emit fp32 + bf16
__global__ __launch_bounds__(256) void reduce_xdbl_k(
    const float* __restrict__ part, float* __restrict__ xdbl,
    __bf16* __restrict__ xdbl_bf)
{
    const int idx = blockIdx.x * 256 + threadIdx.x;   // over LL*96
    float s = 0.f;
    #pragma unroll
    for (int z = 0; z < KSPL; ++z) s += part[(size_t)z * (LL * 96) + idx];
    xdbl[idx] = s;
    xdbl_bf[idx] = (__bf16)s;
}

// ---------------------------------------------------------------------------
// bf16 MFMA GEMM, 128x128 tile (in_proj): C = A @ W^T (+bias)(+act), fp32 out.
// 4 waves as 2x2 of 64x64, acc[4][4] of 16x16x32, BK=32, global_load_lds w16.
// ---------------------------------------------------------------------------
template<int BIAS, int ACT>
__global__ __launch_bounds__(256) void gemm_bf16_nt(
    const __bf16* __restrict__ A, int lda,
    const __bf16* __restrict__ W, int ldw,
    const float* __restrict__ bias,
    float* __restrict__ C, int ldc,
    int K)
{
    __shared__ __bf16 smA[128 * 32];
    __shared__ __bf16 smB[128 * 32];
    const int t    = threadIdx.x;
    const int lane = t & 63;
    const int m0 = blockIdx.y * 128, n0 = blockIdx.x * 128;
    const int wr = ((t >> 6) >> 1) * 64;
    const int wc = ((t >> 6) & 1) * 64;

    const int srow = t >> 2;                    // 0..63
    const int skof = (t & 3) * 8;               // 0/8/16/24
    const int lds_base = (t >> 6) * 512;        // elements (wave-uniform)

    const int offA = (wr + (lane & 15)) * 32 + ((lane >> 4) * 8);
    const int offB = (wc + (lane & 15)) * 32 + ((lane >> 4) * 8);

    f32x4 acc[4][4] = {};

    for (int k0 = 0; k0 < K; k0 += 32) {
        gload16(A + (size_t)(m0 + srow)      * lda + k0 + skof, &smA[lds_base]);
        gload16(A + (size_t)(m0 + 64 + srow) * lda + k0 + skof, &smA[2048 + lds_base]);
        gload16(W + (size_t)(n0 + srow)      * ldw + k0 + skof, &smB[lds_base]);
        gload16(W + (size_t)(n0 + 64 + srow) * ldw + k0 + skof, &smB[2048 + lds_base]);
        __syncthreads();

        bf16x8 af[4], bfr[4];
        #pragma unroll
        for (int m = 0; m < 4; ++m) af[m]  = *(const bf16x8*)&smA[offA + m * 512];
        #pragma unroll
        for (int n = 0; n < 4; ++n) bfr[n] = *(const bf16x8*)&smB[offB + n * 512];
        #pragma unroll
        for (int m = 0; m < 4; ++m)
            #pragma unroll
            for (int n = 0; n < 4; ++n)
                acc[m][n] = __builtin_amdgcn_mfma_f32_16x16x32_bf16(
                    af[m], bfr[n], acc[m][n], 0, 0, 0);
        __syncthreads();
    }

    const int rbase = m0 + wr + ((lane >> 4) << 2);
    const int cbase = n0 + wc + (lane & 15);
    #pragma unroll
    for (int n = 0; n < 4; ++n) {
        const int col = cbase + n * 16;
        const float bv = BIAS ? bias[col] : 0.f;
        #pragma unroll
        for (int m = 0; m < 4; ++m) {
            #pragma unroll
            for (int j = 0; j < 4; ++j) {
                float v = acc[m][n][j] + bv;
                if (ACT == 1) v = softplus_f(v);
                C[(size_t)(rbase + m * 16 + j) * ldc + col] = v;
            }
        }
    }
}

// ---------------------------------------------------------------------------
// bf16 MFMA GEMM, 64x128 tile: doubles the block count for small-N GEMMs
// (out_proj / dt_proj / x_proj splitK). 4 waves as 2x2 of 32x64, acc[2][4].
// grid = (N/128, M/64, SPLITK). ncols guards C writes (padded W rows).
// ---------------------------------------------------------------------------
template<int BIAS, int ACT, int SPLITK>
__global__ __launch_bounds__(256) void gemm64_bf16_nt(
    const __bf16* __restrict__ A, int lda,
    const __bf16* __restrict__ W, int ldw,
    const float* __restrict__ bias,
    float* __restrict__ C, int ldc, int ncols, size_t pstride,
    int K)
{
    __shared__ __bf16 smA[64 * 32];
    __shared__ __bf16 smB[128 * 32];
    const int t    = threadIdx.x;
    const int lane = t & 63;
    const int m0 = blockIdx.y * 64, n0 = blockIdx.x * 128;
    const int wr = ((t >> 6) >> 1) * 32;        // 0/32
    const int wc = ((t >> 6) & 1) * 64;         // 0/64

    const int srow = t >> 2;                    // 0..63
    const int skof = (t & 3) * 8;
    const int lds_base = (t >> 6) * 512;

    const int offA = (wr + (lane & 15)) * 32 + ((lane >> 4) * 8);
    const int offB = (wc + (lane & 15)) * 32 + ((lane >> 4) * 8);

    const int kseg  = K / SPLITK;
    const int kbase = (SPLITK > 1) ? blockIdx.z * kseg : 0;

    f32x4 acc[2][4] = {};

    for (int k0 = kbase; k0 < kbase + kseg; k0 += 32) {
        gload16(A + (size_t)(m0 + srow)      * lda + k0 + skof, &smA[lds_base]);
        gload16(W + (size_t)(n0 + srow)      * ldw + k0 + skof, &smB[lds_base]);
        gload16(W + (size_t)(n0 + 64 + srow) * ldw + k0 + skof, &smB[2048 + lds_base]);
        __syncthreads();

        bf16x8 af[2], bfr[4];
        #pragma unroll
        for (int m = 0; m < 2; ++m) af[m]  = *(const bf16x8*)&smA[offA + m * 512];
        #pragma unroll
        for (int n = 0; n < 4; ++n) bfr[n] = *(const bf16x8*)&smB[offB + n * 512];
        #pragma unroll
        for (int m = 0; m < 2; ++m)
            #pragma unroll
            for (int n = 0; n < 4; ++n)
                acc[m][n] = __builtin_amdgcn_mfma_f32_16x16x32_bf16(
                    af[m], bfr[n], acc[m][n], 0, 0, 0);
        __syncthreads();
    }

    float* Cp = C + ((SPLITK > 1) ? (size_t)blockIdx.z * pstride : 0);
    const int rbase = m0 + wr + ((lane >> 4) << 2);
    const int cbase = n0 + wc + (lane & 15);
    #pragma unroll
    for (int n = 0; n < 4; ++n) {
        const int col = cbase + n * 16;
        if (col >= ncols) continue;
        const float bv = BIAS ? bias[col] : 0.f;
        #pragma unroll
        for (int m = 0; m < 2; ++m) {
            #pragma unroll
            for (int j = 0; j < 4; ++j) {
                float v = acc[m][n][j] + bv;
                if (ACT == 1) v = softplus_f(v);
                Cp[(size_t)(rbase + m * 16 + j) * ldc + col] = v;
            }
        }
    }
}

// ---------------------------------------------------------------------------
// Causal depthwise conv (K=4) + bias + silu; emits fp32 and bf16.
// ---------------------------------------------------------------------------
__global__ __launch_bounds__(256) void conv_silu_k(
    const float* __restrict__ xr, const float* __restrict__ cw,
    const float* __restrict__ cb, float* __restrict__ xs,
    __bf16* __restrict__ xs_bf)
{
    const int idx = blockIdx.x * 256 + threadIdx.x;
    const int l = idx >> 11;
    const int d = idx & (DI - 1);
    float acc = cb[d];
    const float w0 = cw[d*4+0], w1 = cw[d*4+1], w2 = cw[d*4+2], w3 = cw[d*4+3];
    if (l >= 3) acc = fmaf(xr[(size_t)(l-3)*(2*DI) + d], w0, acc);
    if (l >= 2) acc = fmaf(xr[(size_t)(l-2)*(2*DI) + d], w1, acc);
    if (l >= 1) acc = fmaf(xr[(size_t)(l-1)*(2*DI) + d], w2, acc);
    acc = fmaf(xr[(size_t)l*(2*DI) + d], w3, acc);
    const float s = silu_f(acc);
    xs[idx] = s;
    xs_bf[idx] = (__bf16)s;
}

// ---------------------------------------------------------------------------
// Scan phase 1: per-(chunk, channel) local scan, h=0 start.
// ---------------------------------------------------------------------------
__global__ __launch_bounds__(256) void scan1_k(
    const float* __restrict__ delta, const float* __restrict__ xs,
    const float* __restrict__ A_log, const float* __restrict__ xdbl,
    float* __restrict__ P, float* __restrict__ S)
{
    const int d = blockIdx.x * 256 + threadIdx.x;
    const int c = blockIdx.y;
    float A[NS];
    #pragma unroll
    for (int n = 0; n < NS; ++n) A[n] = -__expf(A_log[d * NS + n]);
    float h[NS] = {};
    float ap[NS];
    #pragma unroll
    for (int n = 0; n < NS; ++n) ap[n] = 1.f;

    const int l0 = c * CL;
    for (int l = l0; l < l0 + CL; ++l) {
        const float dt = delta[(size_t)l * DI + d];
        const float u  = xs[(size_t)l * DI + d];
        const float du = dt * u;
        #pragma unroll
        for (int n = 0; n < NS; ++n) {
            const float Bn = xdbl[(size_t)l * 96 + RR + n];
            const float dA = __expf(dt * A[n]);
            h[n]  = fmaf(dA, h[n], du * Bn);
            ap[n] *= dA;
        }
    }
    const size_t base = ((size_t)c * DI + d) * NS;
    #pragma unroll
    for (int n = 0; n < NS; ++n) { P[base + n] = ap[n]; S[base + n] = h[n]; }
}

// ---------------------------------------------------------------------------
// Scan phase 2: sequential over NC chunks; exclusive prefix per (d,n).
// ---------------------------------------------------------------------------
__global__ __launch_bounds__(256) void scan2_k(
    const float* __restrict__ P, const float* __restrict__ S, float* __restrict__ Hp)
{
    const int idx = blockIdx.x * 256 + threadIdx.x;
    float h = 0.f;
    for (int c = 0; c < NC; ++c) {
        const size_t o = (size_t)c * DI * NS + idx;
        Hp[o] = h;
        h = fmaf(P[o], h, S[o]);
    }
}

// ---------------------------------------------------------------------------
// Scan phase 3: replay with prefix, y = (h.C + xs*D)*silu(res), write bf16.
// ---------------------------------------------------------------------------
__global__ __launch_bounds__(256) void scan3_k(
    const float* __restrict__ delta, const float* __restrict__ xs,
    const float* __restrict__ A_log, const float* __restrict__ xdbl,
    const float* __restrict__ Hp, const float* __restrict__ xr,
    const float* __restrict__ Dp, __bf16* __restrict__ y_bf)
{
    const int d = blockIdx.x * 256 + threadIdx.x;
    const int c = blockIdx.y;
    float A[NS];
    #pragma unroll
    for (int n = 0; n < NS; ++n) A[n] = -__expf(A_log[d * NS + n]);
    float h[NS];
    const size_t base = ((size_t)c * DI + d) * NS;
    #pragma unroll
    for (int n = 0; n < NS; ++n) h[n] = Hp[base + n];
    const float Dd = Dp[d];

    const int l0 = c * CL;
    for (int l = l0; l < l0 + CL; ++l) {
        const float dt = delta[(size_t)l * DI + d];
        const float u  = xs[(size_t)l * DI + d];
        const float du = dt * u;
        float acc = 0.f;
        #pragma unroll
        for (int n = 0; n < NS; ++n) {
            const float Bn = xdbl[(size_t)l * 96 + RR + n];
            const float Cn = xdbl[(size_t)l * 96 + RR + NS + n];
            const float dA = __expf(dt * A[n]);
            h[n] = fmaf(dA, h[n], du * Bn);
            acc  = fmaf(h[n], Cn, acc);
        }
        float yv = fmaf(u, Dd, acc);
        const float r = xr[(size_t)l * (2*DI) + DI + d];
        yv *= silu_f(r);
        y_bf[(size_t)l * DI + d] = (__bf16)yv;
    }
}

// ---------------------------------------------------------------------------
extern "C" void kernel_launch(void* const* d_in, const int* in_sizes, int n_in,
                              void* d_out, int out_size, void* d_ws, size_t ws_size,
                              hipStream_t stream)
{
    const float* x        = (const float*)d_in[0];   // [L][H]
    const float* in_w     = (const float*)d_in[1];   // [2DI][H]
    const float* in_b     = (const float*)d_in[2];   // [2DI]
    const float* conv_w   = (const float*)d_in[3];   // [DI][1][4]
    const float* conv_b   = (const float*)d_in[4];   // [DI]
    const float* xproj_w  = (const float*)d_in[5];   // [96][DI]
    const float* dtproj_w = (const float*)d_in[6];   // [DI][R]
    const float* dtproj_b = (const float*)d_in[7];   // [DI]
    const float* A_log    = (const float*)d_in[8];   // [DI][N]
    const float* Dp       = (const float*)d_in[9];   // [DI]
    const float* outw     = (const float*)d_in[10];  // [H][DI]
    float* out = (float*)d_out;                      // [L][H]

    // fp32 workspace
    float* ws    = (float*)d_ws;
    float* xr    = ws;                                 // [L][2DI]
    float* xs    = xr    + (size_t)LL * 2 * DI;        // [L][DI]
    float* xdbl  = xs    + (size_t)LL * DI;            // [L][96]
    float* delta = xdbl  + (size_t)LL * 96;            // [L][DI] (splitK partials alias)
    float* P     = delta + (size_t)LL * DI;            // [NC][DI][NS]
    float* S     = P     + (size_t)NC * DI * NS;
    float* Hp    = S     + (size_t)NC * DI * NS;
    float* xpart = delta;                              // [KSPL][L][96], consumed before delta written
    // bf16 workspace
    __bf16* x_bf    = (__bf16*)(Hp + (size_t)NC * DI * NS);
    __bf16* inw_bf  = x_bf    + (size_t)LL * H_DIM;       // [2DI][H]
    __bf16* outw_bf = inw_bf  + (size_t)2 * DI * H_DIM;   // [H][DI]
    __bf16* dtw_bf  = outw_bf + (size_t)H_DIM * DI;       // [DI][R]
    __bf16* xdbl_bf = dtw_bf  + (size_t)DI * RR;          // [L][96]
    __bf16* y_bf    = xdbl_bf + (size_t)LL * 96;          // [L][DI]
    __bf16* xs_bf   = y_bf    + (size_t)LL * DI;          // [L][DI]
    __bf16* xpw_pad = xs_bf   + (size_t)LL * DI;          // [128][DI]

    const dim3 blk(256);

    // 0) all fp32->bf16 conversions + x_proj weight pad, one kernel
    convert_all_k<<<dim3(CUMT / 1024), blk, 0, stream>>>(
        x, in_w, outw, dtproj_w, xproj_w,
        x_bf, inw_bf, outw_bf, dtw_bf, xpw_pad);

    // 1) x_and_res = x @ in_proj_w^T + in_proj_b           [L][2DI] fp32
    gemm_bf16_nt<1,0><<<dim3((2*DI)/128, LL/128), blk, 0, stream>>>(
        x_bf, H_DIM, inw_bf, H_DIM, in_b, xr, 2*DI, H_DIM);

    // 2) xs = silu(conv(xc) + conv_b)                      [L][DI] fp32+bf16
    conv_silu_k<<<dim3((LL*DI)/256), blk, 0, stream>>>(xr, conv_w, conv_b, xs, xs_bf);

    // 3) x_dbl = xs @ x_proj_w^T  (split-K MFMA + reduce)  [L][96] fp32+bf16
    gemm64_bf16_nt<0,0,KSPL><<<dim3(1, LL/64, KSPL), blk, 0, stream>>>(
        xs_bf, DI, xpw_pad, DI, nullptr, xpart, 96, 96, (size_t)LL * 96, DI);
    reduce_xdbl_k<<<dim3((LL * 96) / 256), blk, 0, stream>>>(xpart, xdbl, xdbl_bf);

    // 4) delta = softplus(x_dbl[:, :64] @ dt_proj_w^T + b) [L][DI]
    gemm64_bf16_nt<1,1,1><<<dim3(DI/128, LL/64), blk, 0, stream>>>(
        xdbl_bf, 96, dtw_bf, RR, dtproj_b, delta, DI, DI, 0, RR);

    // 5-7) chunked scan; scan3 emits y as bf16
    scan1_k<<<dim3(DI/256, NC), blk, 0, stream>>>(delta, xs, A_log, xdbl, P, S);
    scan2_k<<<dim3((DI*NS)/256), blk, 0, stream>>>(P, S, Hp);
    scan3_k<<<dim3(DI/256, NC), blk, 0, stream>>>(delta, xs, A_log, xdbl, Hp, xr, Dp, y_bf);

    // 8) out = y @ out_proj_w^T                            [L][H]
    gemm64_bf16_nt<0,0,1><<<dim3(H_DIM/128, LL/64), blk, 0, stream>>>(
        y_bf, DI, outw_bf, DI, nullptr, out, H_DIM, H_DIM, 0, DI);
}

// Round 6
// 268.954 us; speedup vs baseline: 2.5274x; 1.0167x over previous
//
#include <hip/hip_runtime.h>
#include <hip/hip_bf16.h>
#include <math.h>

// Mamba forward, B=1, L=2048, H=1024, DI=2048, N=16, R=64, K=4
#define H_DIM 1024
#define DI    2048
#define NS    16
#define RR    64
#define LL    2048
#define NC    32   // chunks for the parallel scan
#define CL    64   // chunk length = LL/NC
#define KSPL  16   // split-K factor for x_proj

typedef __bf16 bf16x8 __attribute__((ext_vector_type(8)));
typedef __bf16 bf16x4 __attribute__((ext_vector_type(4)));
typedef float  f32x4  __attribute__((ext_vector_type(4)));

__device__ __forceinline__ float silu_f(float x)  { return x / (1.f + __expf(-x)); }
// Cheap softplus: hw exp/log only (log1pf libm slow path caused acc spills).
__device__ __forceinline__ float softplus_f(float x) {
    const float l = __logf(1.f + __expf(x));
    return x > 15.f ? x : l;
}

__device__ __forceinline__ void gload16(const void* g, void* l) {
    __builtin_amdgcn_global_load_lds(
        (const __attribute__((address_space(1))) void*)g,
        (__attribute__((address_space(3))) void*)l, 16, 0, 0);
}

__device__ __forceinline__ void f2b4(const float* __restrict__ in,
                                     __bf16* __restrict__ out)
{
    float4 v = *(const float4*)in;
    bf16x4 o;
    o[0] = (__bf16)v.x; o[1] = (__bf16)v.y; o[2] = (__bf16)v.z; o[3] = (__bf16)v.w;
    *(bf16x4*)out = o;
}

// ---------------------------------------------------------------------------
// One fused conversion kernel: x, in_w, outw, dtw (f2b) + x_proj_w pad.
// ---------------------------------------------------------------------------
#define SEG0 (LL * H_DIM)          // x
#define SEG1 (2 * DI * H_DIM)      // in_w
#define SEG2 (H_DIM * DI)          // outw
#define SEG3 (DI * RR)             // dtw
#define SEG4 (128 * DI)            // xpw_pad
#define CUM0 SEG0
#define CUM1 (CUM0 + SEG1)
#define CUM2 (CUM1 + SEG2)
#define CUM3 (CUM2 + SEG3)
#define CUMT (CUM3 + SEG4)

__global__ __launch_bounds__(256) void convert_all_k(
    const float* __restrict__ x,    const float* __restrict__ in_w,
    const float* __restrict__ outw, const float* __restrict__ dtw,
    const float* __restrict__ xpw,
    __bf16* __restrict__ x_bf,    __bf16* __restrict__ inw_bf,
    __bf16* __restrict__ outw_bf, __bf16* __restrict__ dtw_bf,
    __bf16* __restrict__ xpw_pad)
{
    const int i = (blockIdx.x * 256 + threadIdx.x) * 4;
    if (i < CUM0) {
        f2b4(x + i, x_bf + i);
    } else if (i < CUM1) {
        const int o = i - CUM0;  f2b4(in_w + o, inw_bf + o);
    } else if (i < CUM2) {
        const int o = i - CUM1;  f2b4(outw + o, outw_bf + o);
    } else if (i < CUM3) {
        const int o = i - CUM2;  f2b4(dtw + o, dtw_bf + o);
    } else if (i < CUMT) {
        const int o = i - CUM3;           // over [128][2048]
        const int row = o >> 11;
        if (row < 96) {
            f2b4(xpw + o, xpw_pad + o);
        } else {
            bf16x4 z; z[0] = z[1] = z[2] = z[3] = (__bf16)0.f;
            *(bf16x4*)&xpw_pad[o] = z;
        }
    }
}

// sum the KSPL split-K partials of x_dbl; emit fp32 + bf16
__global__ __launch_bounds__(256) void reduce_xdbl_k(
    const float* __restrict__ part, float* __restrict__ xdbl,
    __bf16* __restrict__ xdbl_bf)
{
    const int idx = blockIdx.x * 256 + threadIdx.x;   // over LL*96
    float s = 0.f;
    #pragma unroll
    for (int z = 0; z < KSPL; ++z) s += part[(size_t)z * (LL * 96) + idx];
    xdbl[idx] = s;
    xdbl_bf[idx] = (__bf16)s;
}

// ---------------------------------------------------------------------------
// in_proj GEMM: 128x128 tile, writes bf16 xc / res split halves directly.
// x_and_res[l, c] = x @ in_w^T + b;  c < DI -> xc_bf, else res_bf.
// ---------------------------------------------------------------------------
__global__ __launch_bounds__(256) void gemm_inproj_k(
    const __bf16* __restrict__ A,        // [L][H]
    const __bf16* __restrict__ W,        // [2DI][H]
    const float* __restrict__ bias,
    __bf16* __restrict__ xc_bf,          // [L][DI]
    __bf16* __restrict__ res_bf)         // [L][DI]
{
    __shared__ __bf16 smA[128 * 32];
    __shared__ __bf16 smB[128 * 32];
    const int t    = threadIdx.x;
    const int lane = t & 63;
    const int m0 = blockIdx.y * 128, n0 = blockIdx.x * 128;
    const int wr = ((t >> 6) >> 1) * 64;
    const int wc = ((t >> 6) & 1) * 64;

    const int srow = t >> 2;
    const int skof = (t & 3) * 8;
    const int lds_base = (t >> 6) * 512;

    const int offA = (wr + (lane & 15)) * 32 + ((lane >> 4) * 8);
    const int offB = (wc + (lane & 15)) * 32 + ((lane >> 4) * 8);

    f32x4 acc[4][4] = {};

    for (int k0 = 0; k0 < H_DIM; k0 += 32) {
        gload16(A + (size_t)(m0 + srow)      * H_DIM + k0 + skof, &smA[lds_base]);
        gload16(A + (size_t)(m0 + 64 + srow) * H_DIM + k0 + skof, &smA[2048 + lds_base]);
        gload16(W + (size_t)(n0 + srow)      * H_DIM + k0 + skof, &smB[lds_base]);
        gload16(W + (size_t)(n0 + 64 + srow) * H_DIM + k0 + skof, &smB[2048 + lds_base]);
        __syncthreads();

        bf16x8 af[4], bfr[4];
        #pragma unroll
        for (int m = 0; m < 4; ++m) af[m]  = *(const bf16x8*)&smA[offA + m * 512];
        #pragma unroll
        for (int n = 0; n < 4; ++n) bfr[n] = *(const bf16x8*)&smB[offB + n * 512];
        #pragma unroll
        for (int m = 0; m < 4; ++m)
            #pragma unroll
            for (int n = 0; n < 4; ++n)
                acc[m][n] = __builtin_amdgcn_mfma_f32_16x16x32_bf16(
                    af[m], bfr[n], acc[m][n], 0, 0, 0);
        __syncthreads();
    }

    // entire block's col range is on one side of DI (n0 is 128-aligned)
    __bf16* outp = (n0 < DI) ? xc_bf : res_bf;
    const int ncol0 = (n0 < DI) ? n0 : n0 - DI;
    const int rbase = m0 + wr + ((lane >> 4) << 2);
    const int cbase = ncol0 + wc + (lane & 15);
    #pragma unroll
    for (int n = 0; n < 4; ++n) {
        const int col = cbase + n * 16;
        const float bv = bias[(n0 < DI ? 0 : DI) + col];
        #pragma unroll
        for (int m = 0; m < 4; ++m)
            #pragma unroll
            for (int j = 0; j < 4; ++j)
                outp[(size_t)(rbase + m * 16 + j) * DI + col] =
                    (__bf16)(acc[m][n][j] + bv);
    }
}

// ---------------------------------------------------------------------------
// bf16 MFMA GEMM, 64x128 tile (out_proj / dt_proj / x_proj splitK).
// grid = (N/128, M/64, SPLITK). ncols guards C writes (padded W rows).
// ---------------------------------------------------------------------------
template<int BIAS, int ACT, int SPLITK>
__global__ __launch_bounds__(256) void gemm64_bf16_nt(
    const __bf16* __restrict__ A, int lda,
    const __bf16* __restrict__ W, int ldw,
    const float* __restrict__ bias,
    float* __restrict__ C, int ldc, int ncols, size_t pstride,
    int K)
{
    __shared__ __bf16 smA[64 * 32];
    __shared__ __bf16 smB[128 * 32];
    const int t    = threadIdx.x;
    const int lane = t & 63;
    const int m0 = blockIdx.y * 64, n0 = blockIdx.x * 128;
    const int wr = ((t >> 6) >> 1) * 32;
    const int wc = ((t >> 6) & 1) * 64;

    const int srow = t >> 2;
    const int skof = (t & 3) * 8;
    const int lds_base = (t >> 6) * 512;

    const int offA = (wr + (lane & 15)) * 32 + ((lane >> 4) * 8);
    const int offB = (wc + (lane & 15)) * 32 + ((lane >> 4) * 8);

    const int kseg  = K / SPLITK;
    const int kbase = (SPLITK > 1) ? blockIdx.z * kseg : 0;

    f32x4 acc[2][4] = {};

    for (int k0 = kbase; k0 < kbase + kseg; k0 += 32) {
        gload16(A + (size_t)(m0 + srow)      * lda + k0 + skof, &smA[lds_base]);
        gload16(W + (size_t)(n0 + srow)      * ldw + k0 + skof, &smB[lds_base]);
        gload16(W + (size_t)(n0 + 64 + srow) * ldw + k0 + skof, &smB[2048 + lds_base]);
        __syncthreads();

        bf16x8 af[2], bfr[4];
        #pragma unroll
        for (int m = 0; m < 2; ++m) af[m]  = *(const bf16x8*)&smA[offA + m * 512];
        #pragma unroll
        for (int n = 0; n < 4; ++n) bfr[n] = *(const bf16x8*)&smB[offB + n * 512];
        #pragma unroll
        for (int m = 0; m < 2; ++m)
            #pragma unroll
            for (int n = 0; n < 4; ++n)
                acc[m][n] = __builtin_amdgcn_mfma_f32_16x16x32_bf16(
                    af[m], bfr[n], acc[m][n], 0, 0, 0);
        __syncthreads();
    }

    float* Cp = C + ((SPLITK > 1) ? (size_t)blockIdx.z * pstride : 0);
    const int rbase = m0 + wr + ((lane >> 4) << 2);
    const int cbase = n0 + wc + (lane & 15);
    #pragma unroll
    for (int n = 0; n < 4; ++n) {
        const int col = cbase + n * 16;
        if (col >= ncols) continue;
        const float bv = BIAS ? bias[col] : 0.f;
        #pragma unroll
        for (int m = 0; m < 2; ++m) {
            #pragma unroll
            for (int j = 0; j < 4; ++j) {
                float v = acc[m][n][j] + bv;
                if (ACT == 1) v = softplus_f(v);
                Cp[(size_t)(rbase + m * 16 + j) * ldc + col] = v;
            }
        }
    }
}

// ---------------------------------------------------------------------------
// Causal depthwise conv (K=4) + bias + silu on bf16 xc; 8 channels/thread.
// ---------------------------------------------------------------------------
__global__ __launch_bounds__(256) void conv_silu_k(
    const __bf16* __restrict__ xc, const float* __restrict__ cw,
    const float* __restrict__ cb, __bf16* __restrict__ xs_bf)
{
    const int idx = blockIdx.x * 256 + threadIdx.x;   // over L*DI/8
    const int l  = idx >> 8;                          // (idx*8) / 2048
    const int d0 = (idx & 255) * 8;

    float r0[8] = {}, r1[8] = {}, r2[8] = {}, r3[8];
    bf16x8 v;
    if (l >= 3) { v = *(const bf16x8*)&xc[(size_t)(l-3)*DI + d0];
                  #pragma unroll
                  for (int j = 0; j < 8; ++j) r0[j] = (float)v[j]; }
    if (l >= 2) { v = *(const bf16x8*)&xc[(size_t)(l-2)*DI + d0];
                  #pragma unroll
                  for (int j = 0; j < 8; ++j) r1[j] = (float)v[j]; }
    if (l >= 1) { v = *(const bf16x8*)&xc[(size_t)(l-1)*DI + d0];
                  #pragma unroll
                  for (int j = 0; j < 8; ++j) r2[j] = (float)v[j]; }
    v = *(const bf16x8*)&xc[(size_t)l*DI + d0];
    #pragma unroll
    for (int j = 0; j < 8; ++j) r3[j] = (float)v[j];

    bf16x8 o;
    #pragma unroll
    for (int j = 0; j < 8; ++j) {
        const int d = d0 + j;
        float4 w = *(const float4*)&cw[d * 4];
        float a = cb[d];
        a = fmaf(r0[j], w.x, a);
        a = fmaf(r1[j], w.y, a);
        a = fmaf(r2[j], w.z, a);
        a = fmaf(r3[j], w.w, a);
        o[j] = (__bf16)silu_f(a);
    }
    *(bf16x8*)&xs_bf[(size_t)l*DI + d0] = o;
}

// ---------------------------------------------------------------------------
// Scan phase 1: per-(chunk, channel) local scan, h=0 start.
// ---------------------------------------------------------------------------
__global__ __launch_bounds__(256) void scan1_k(
    const float* __restrict__ delta, const __bf16* __restrict__ xs,
    const float* __restrict__ A_log, const float* __restrict__ xdbl,
    float* __restrict__ P, float* __restrict__ S)
{
    const int d = blockIdx.x * 256 + threadIdx.x;
    const int c = blockIdx.y;
    float A[NS];
    #pragma unroll
    for (int n = 0; n < NS; ++n) A[n] = -__expf(A_log[d * NS + n]);
    float h[NS] = {};
    float ap[NS];
    #pragma unroll
    for (int n = 0; n < NS; ++n) ap[n] = 1.f;

    const int l0 = c * CL;
    for (int l = l0; l < l0 + CL; ++l) {
        const float dt = delta[(size_t)l * DI + d];
        const float u  = (float)xs[(size_t)l * DI + d];
        const float du = dt * u;
        #pragma unroll
        for (int n = 0; n < NS; ++n) {
            const float Bn = xdbl[(size_t)l * 96 + RR + n];
            const float dA = __expf(dt * A[n]);
            h[n]  = fmaf(dA, h[n], du * Bn);
            ap[n] *= dA;
        }
    }
    const size_t base = ((size_t)c * DI + d) * NS;
    #pragma unroll
    for (int n = 0; n < NS; ++n) { P[base + n] = ap[n]; S[base + n] = h[n]; }
}

// ---------------------------------------------------------------------------
// Scan phase 2: sequential over NC chunks; exclusive prefix per (d,n).
// ---------------------------------------------------------------------------
__global__ __launch_bounds__(256) void scan2_k(
    const float* __restrict__ P, const float* __restrict__ S, float* __restrict__ Hp)
{
    const int idx = blockIdx.x * 256 + threadIdx.x;
    float h = 0.f;
    for (int c = 0; c < NC; ++c) {
        const size_t o = (size_t)c * DI * NS + idx;
        Hp[o] = h;
        h = fmaf(P[o], h, S[o]);
    }
}

// ---------------------------------------------------------------------------
// Scan phase 3: replay with prefix, y = (h.C + xs*D)*silu(res), write bf16.
// ---------------------------------------------------------------------------
__global__ __launch_bounds__(256) void scan3_k(
    const float* __restrict__ delta, const __bf16* __restrict__ xs,
    const float* __restrict__ A_log, const float* __restrict__ xdbl,
    const float* __restrict__ Hp, const __bf16* __restrict__ res_bf,
    const float* __restrict__ Dp, __bf16* __restrict__ y_bf)
{
    const int d = blockIdx.x * 256 + threadIdx.x;
    const int c = blockIdx.y;
    float A[NS];
    #pragma unroll
    for (int n = 0; n < NS; ++n) A[n] = -__expf(A_log[d * NS + n]);
    float h[NS];
    const size_t base = ((size_t)c * DI + d) * NS;
    #pragma unroll
    for (int n = 0; n < NS; ++n) h[n] = Hp[base + n];
    const float Dd = Dp[d];

    const int l0 = c * CL;
    for (int l = l0; l < l0 + CL; ++l) {
        const float dt = delta[(size_t)l * DI + d];
        const float u  = (float)xs[(size_t)l * DI + d];
        const float du = dt * u;
        float acc = 0.f;
        #pragma unroll
        for (int n = 0; n < NS; ++n) {
            const float Bn = xdbl[(size_t)l * 96 + RR + n];
            const float Cn = xdbl[(size_t)l * 96 + RR + NS + n];
            const float dA = __expf(dt * A[n]);
            h[n] = fmaf(dA, h[n], du * Bn);
            acc  = fmaf(h[n], Cn, acc);
        }
        float yv = fmaf(u, Dd, acc);
        const float r = (float)res_bf[(size_t)l * DI + d];
        yv *= silu_f(r);
        y_bf[(size_t)l * DI + d] = (__bf16)yv;
    }
}

// ---------------------------------------------------------------------------
extern "C" void kernel_launch(void* const* d_in, const int* in_sizes, int n_in,
                              void* d_out, int out_size, void* d_ws, size_t ws_size,
                              hipStream_t stream)
{
    const float* x        = (const float*)d_in[0];   // [L][H]
    const float* in_w     = (const float*)d_in[1];   // [2DI][H]
    const float* in_b     = (const float*)d_in[2];   // [2DI]
    const float* conv_w   = (const float*)d_in[3];   // [DI][1][4]
    const float* conv_b   = (const float*)d_in[4];   // [DI]
    const float* xproj_w  = (const float*)d_in[5];   // [96][DI]
    const float* dtproj_w = (const float*)d_in[6];   // [DI][R]
    const float* dtproj_b = (const float*)d_in[7];   // [DI]
    const float* A_log    = (const float*)d_in[8];   // [DI][N]
    const float* Dp       = (const float*)d_in[9];   // [DI]
    const float* outw     = (const float*)d_in[10];  // [H][DI]
    float* out = (float*)d_out;                      // [L][H]

    // fp32 workspace
    float* ws    = (float*)d_ws;
    float* delta = ws;                                 // [L][DI] 16MB (splitK partials alias)
    float* xdbl  = delta + (size_t)LL * DI;            // [L][96]
    float* P     = xdbl  + (size_t)LL * 96;            // [NC][DI][NS]
    float* S     = P     + (size_t)NC * DI * NS;
    float* Hp    = S     + (size_t)NC * DI * NS;
    float* xpart = delta;                              // [KSPL][L][96] = 12.6MB < 16MB
    // bf16 workspace
    __bf16* x_bf    = (__bf16*)(Hp + (size_t)NC * DI * NS);
    __bf16* inw_bf  = x_bf    + (size_t)LL * H_DIM;       // [2DI][H]
    __bf16* outw_bf = inw_bf  + (size_t)2 * DI * H_DIM;   // [H][DI]
    __bf16* dtw_bf  = outw_bf + (size_t)H_DIM * DI;       // [DI][R]
    __bf16* xdbl_bf = dtw_bf  + (size_t)DI * RR;          // [L][96]
    __bf16* y_bf    = xdbl_bf + (size_t)LL * 96;          // [L][DI]
    __bf16* xs_bf   = y_bf    + (size_t)LL * DI;          // [L][DI]
    __bf16* xc_bf   = xs_bf   + (size_t)LL * DI;          // [L][DI]
    __bf16* res_bf  = xc_bf   + (size_t)LL * DI;          // [L][DI]
    __bf16* xpw_pad = res_bf  + (size_t)LL * DI;          // [128][DI]

    const dim3 blk(256);

    // 0) all fp32->bf16 conversions + x_proj weight pad, one kernel
    convert_all_k<<<dim3(CUMT / 1024), blk, 0, stream>>>(
        x, in_w, outw, dtproj_w, xproj_w,
        x_bf, inw_bf, outw_bf, dtw_bf, xpw_pad);

    // 1) x_and_res = x @ in_proj_w^T + b -> bf16 xc | res  [L][2DI]
    gemm_inproj_k<<<dim3((2*DI)/128, LL/128), blk, 0, stream>>>(
        x_bf, inw_bf, in_b, xc_bf, res_bf);

    // 2) xs = silu(conv(xc) + conv_b)                      [L][DI] bf16
    conv_silu_k<<<dim3((LL*DI)/(8*256)), blk, 0, stream>>>(xc_bf, conv_w, conv_b, xs_bf);

    // 3) x_dbl = xs @ x_proj_w^T  (split-K MFMA + reduce)  [L][96] fp32+bf16
    gemm64_bf16_nt<0,0,KSPL><<<dim3(1, LL/64, KSPL), blk, 0, stream>>>(
        xs_bf, DI, xpw_pad, DI, nullptr, xpart, 96, 96, (size_t)LL * 96, DI);
    reduce_xdbl_k<<<dim3((LL * 96) / 256), blk, 0, stream>>>(xpart, xdbl, xdbl_bf);

    // 4) delta = softplus(x_dbl[:, :64] @ dt_proj_w^T + b) [L][DI] fp32
    gemm64_bf16_nt<1,1,1><<<dim3(DI/128, LL/64), blk, 0, stream>>>(
        xdbl_bf, 96, dtw_bf, RR, dtproj_b, delta, DI, DI, 0, RR);

    // 5-7) chunked scan; scan3 emits y as bf16
    scan1_k<<<dim3(DI/256, NC), blk, 0, stream>>>(delta, xs_bf, A_log, xdbl, P, S);
    scan2_k<<<dim3((DI*NS)/256), blk, 0, stream>>>(P, S, Hp);
    scan3_k<<<dim3(DI/256, NC), blk, 0, stream>>>(delta, xs_bf, A_log, xdbl, Hp, res_bf, Dp, y_bf);

    // 8) out = y @ out_proj_w^T                            [L][H]
    gemm64_bf16_nt<0,0,1><<<dim3(H_DIM/128, LL/64), blk, 0, stream>>>(
        y_bf, DI, outw_bf, DI, nullptr, out, H_DIM, H_DIM, 0, DI);
}

// Round 7
// 268.080 us; speedup vs baseline: 2.5356x; 1.0033x over previous
//
#include <hip/hip_runtime.h>
#include <hip/hip_bf16.h>
#include <math.h>

// Mamba forward, B=1, L=2048, H=1024, DI=2048, N=16, R=64, K=4
#define H_DIM 1024
#define DI    2048
#define NS    16
#define RR    64
#define LL    2048
#define NC    32   // chunks for the parallel scan
#define CL    64   // chunk length = LL/NC
#define KSPL  16   // split-K factor for x_proj

typedef __bf16 bf16x8 __attribute__((ext_vector_type(8)));
typedef __bf16 bf16x4 __attribute__((ext_vector_type(4)));
typedef float  f32x4  __attribute__((ext_vector_type(4)));

__device__ __forceinline__ float silu_f(float x)  { return x / (1.f + __expf(-x)); }
// Cheap softplus: hw exp/log only (log1pf libm slow path caused acc spills).
__device__ __forceinline__ float softplus_f(float x) {
    const float l = __logf(1.f + __expf(x));
    return x > 15.f ? x : l;
}

__device__ __forceinline__ void gload16(const void* g, void* l) {
    __builtin_amdgcn_global_load_lds(
        (const __attribute__((address_space(1))) void*)g,
        (__attribute__((address_space(3))) void*)l, 16, 0, 0);
}

__device__ __forceinline__ void f2b4(const float* __restrict__ in,
                                     __bf16* __restrict__ out)
{
    float4 v = *(const float4*)in;
    bf16x4 o;
    o[0] = (__bf16)v.x; o[1] = (__bf16)v.y; o[2] = (__bf16)v.z; o[3] = (__bf16)v.w;
    *(bf16x4*)out = o;
}

// XCD-aware chunked swizzle over a 2D grid (requires nwg % 8 == 0).
__device__ __forceinline__ void xcd_swz(int nx, int ny, int& bx, int& by)
{
    const int nwg = nx * ny;
    const int bid = by * nx + bx;
    const int cpx = nwg >> 3;
    const int s   = (bid & 7) * cpx + (bid >> 3);
    bx = s % nx;  by = s / nx;
}

// ---------------------------------------------------------------------------
// One fused conversion kernel: x, in_w, outw, dtw (f2b) + x_proj_w pad.
// ---------------------------------------------------------------------------
#define SEG0 (LL * H_DIM)          // x
#define SEG1 (2 * DI * H_DIM)      // in_w
#define SEG2 (H_DIM * DI)          // outw
#define SEG3 (DI * RR)             // dtw
#define SEG4 (128 * DI)            // xpw_pad
#define CUM0 SEG0
#define CUM1 (CUM0 + SEG1)
#define CUM2 (CUM1 + SEG2)
#define CUM3 (CUM2 + SEG3)
#define CUMT (CUM3 + SEG4)

__global__ __launch_bounds__(256) void convert_all_k(
    const float* __restrict__ x,    const float* __restrict__ in_w,
    const float* __restrict__ outw, const float* __restrict__ dtw,
    const float* __restrict__ xpw,
    __bf16* __restrict__ x_bf,    __bf16* __restrict__ inw_bf,
    __bf16* __restrict__ outw_bf, __bf16* __restrict__ dtw_bf,
    __bf16* __restrict__ xpw_pad)
{
    const int i = (blockIdx.x * 256 + threadIdx.x) * 4;
    if (i < CUM0) {
        f2b4(x + i, x_bf + i);
    } else if (i < CUM1) {
        const int o = i - CUM0;  f2b4(in_w + o, inw_bf + o);
    } else if (i < CUM2) {
        const int o = i - CUM1;  f2b4(outw + o, outw_bf + o);
    } else if (i < CUM3) {
        const int o = i - CUM2;  f2b4(dtw + o, dtw_bf + o);
    } else if (i < CUMT) {
        const int o = i - CUM3;           // over [128][2048]
        const int row = o >> 11;
        if (row < 96) {
            f2b4(xpw + o, xpw_pad + o);
        } else {
            bf16x4 z; z[0] = z[1] = z[2] = z[3] = (__bf16)0.f;
            *(bf16x4*)&xpw_pad[o] = z;
        }
    }
}

// sum the KSPL split-K partials of x_dbl; emit fp32 + bf16
__global__ __launch_bounds__(256) void reduce_xdbl_k(
    const float* __restrict__ part, float* __restrict__ xdbl,
    __bf16* __restrict__ xdbl_bf)
{
    const int idx = blockIdx.x * 256 + threadIdx.x;   // over LL*96
    float s = 0.f;
    #pragma unroll
    for (int z = 0; z < KSPL; ++z) s += part[(size_t)z * (LL * 96) + idx];
    xdbl[idx] = s;
    xdbl_bf[idx] = (__bf16)s;
}

// ---------------------------------------------------------------------------
// in_proj GEMM: 128x128 tile, 2-phase double-buffered LDS (one barrier per
// K-step; next tile's global_load_lds in flight across current compute).
// Writes bf16 xc / res split halves directly.
// ---------------------------------------------------------------------------
__global__ __launch_bounds__(256) void gemm_inproj_k(
    const __bf16* __restrict__ A,        // [L][H]
    const __bf16* __restrict__ W,        // [2DI][H]
    const float* __restrict__ bias,
    __bf16* __restrict__ xc_bf,          // [L][DI]
    __bf16* __restrict__ res_bf)         // [L][DI]
{
    __shared__ __bf16 smA[2][128 * 32];
    __shared__ __bf16 smB[2][128 * 32];
    const int t    = threadIdx.x;
    const int lane = t & 63;
    int bx = blockIdx.x, by = blockIdx.y;
    xcd_swz(32, 16, bx, by);              // grid (32,16) = 512 = 64/XCD
    const int m0 = by * 128, n0 = bx * 128;
    const int wr = ((t >> 6) >> 1) * 64;
    const int wc = ((t >> 6) & 1) * 64;

    const int srow = t >> 2;
    const int skof = (t & 3) * 8;
    const int lds_base = (t >> 6) * 512;

    const int offA = (wr + (lane & 15)) * 32 + ((lane >> 4) * 8);
    const int offB = (wc + (lane & 15)) * 32 + ((lane >> 4) * 8);

    f32x4 acc[4][4] = {};

#define STAGE_IP(buf, k0)                                                          \
    do {                                                                           \
        gload16(A + (size_t)(m0 + srow)      * H_DIM + (k0) + skof, &smA[buf][lds_base]);        \
        gload16(A + (size_t)(m0 + 64 + srow) * H_DIM + (k0) + skof, &smA[buf][2048 + lds_base]); \
        gload16(W + (size_t)(n0 + srow)      * H_DIM + (k0) + skof, &smB[buf][lds_base]);        \
        gload16(W + (size_t)(n0 + 64 + srow) * H_DIM + (k0) + skof, &smB[buf][2048 + lds_base]); \
    } while (0)

    STAGE_IP(0, 0);
    __syncthreads();
    int cur = 0;
    for (int k0 = 0; k0 < H_DIM; k0 += 32) {
        if (k0 + 32 < H_DIM) STAGE_IP(cur ^ 1, k0 + 32);

        bf16x8 af[4], bfr[4];
        #pragma unroll
        for (int m = 0; m < 4; ++m) af[m]  = *(const bf16x8*)&smA[cur][offA + m * 512];
        #pragma unroll
        for (int n = 0; n < 4; ++n) bfr[n] = *(const bf16x8*)&smB[cur][offB + n * 512];
        #pragma unroll
        for (int m = 0; m < 4; ++m)
            #pragma unroll
            for (int n = 0; n < 4; ++n)
                acc[m][n] = __builtin_amdgcn_mfma_f32_16x16x32_bf16(
                    af[m], bfr[n], acc[m][n], 0, 0, 0);
        __syncthreads();   // drains vmcnt (next tile ready) + guards reuse
        cur ^= 1;
    }
#undef STAGE_IP

    // entire block's col range is on one side of DI (n0 is 128-aligned)
    __bf16* outp = (n0 < DI) ? xc_bf : res_bf;
    const int ncol0 = (n0 < DI) ? n0 : n0 - DI;
    const int rbase = m0 + wr + ((lane >> 4) << 2);
    const int cbase = ncol0 + wc + (lane & 15);
    #pragma unroll
    for (int n = 0; n < 4; ++n) {
        const int col = cbase + n * 16;
        const float bv = bias[(n0 < DI ? 0 : DI) + col];
        #pragma unroll
        for (int m = 0; m < 4; ++m)
            #pragma unroll
            for (int j = 0; j < 4; ++j)
                outp[(size_t)(rbase + m * 16 + j) * DI + col] =
                    (__bf16)(acc[m][n][j] + bv);
    }
}

// ---------------------------------------------------------------------------
// bf16 MFMA GEMM, 64x128 tile, 2-phase double-buffered (out_proj / dt_proj /
// x_proj splitK). grid = (N/128, M/64, SPLITK). ncols guards C writes.
// ---------------------------------------------------------------------------
template<int BIAS, int ACT, int SPLITK, int SWZ>
__global__ __launch_bounds__(256) void gemm64_bf16_nt(
    const __bf16* __restrict__ A, int lda,
    const __bf16* __restrict__ W, int ldw,
    const float* __restrict__ bias,
    float* __restrict__ C, int ldc, int ncols, size_t pstride,
    int K)
{
    __shared__ __bf16 smA[2][64 * 32];
    __shared__ __bf16 smB[2][128 * 32];
    const int t    = threadIdx.x;
    const int lane = t & 63;
    int bx = blockIdx.x, by = blockIdx.y;
    if (SWZ) xcd_swz(gridDim.x, gridDim.y, bx, by);
    const int m0 = by * 64, n0 = bx * 128;
    const int wr = ((t >> 6) >> 1) * 32;
    const int wc = ((t >> 6) & 1) * 64;

    const int srow = t >> 2;
    const int skof = (t & 3) * 8;
    const int lds_base = (t >> 6) * 512;

    const int offA = (wr + (lane & 15)) * 32 + ((lane >> 4) * 8);
    const int offB = (wc + (lane & 15)) * 32 + ((lane >> 4) * 8);

    const int kseg  = K / SPLITK;
    const int kbase = (SPLITK > 1) ? blockIdx.z * kseg : 0;
    const int kend  = kbase + kseg;

    f32x4 acc[2][4] = {};

#define STAGE_64(buf, k0)                                                          \
    do {                                                                           \
        gload16(A + (size_t)(m0 + srow)      * lda + (k0) + skof, &smA[buf][lds_base]);        \
        gload16(W + (size_t)(n0 + srow)      * ldw + (k0) + skof, &smB[buf][lds_base]);        \
        gload16(W + (size_t)(n0 + 64 + srow) * ldw + (k0) + skof, &smB[buf][2048 + lds_base]); \
    } while (0)

    STAGE_64(0, kbase);
    __syncthreads();
    int cur = 0;
    for (int k0 = kbase; k0 < kend; k0 += 32) {
        if (k0 + 32 < kend) STAGE_64(cur ^ 1, k0 + 32);

        bf16x8 af[2], bfr[4];
        #pragma unroll
        for (int m = 0; m < 2; ++m) af[m]  = *(const bf16x8*)&smA[cur][offA + m * 512];
        #pragma unroll
        for (int n = 0; n < 4; ++n) bfr[n] = *(const bf16x8*)&smB[cur][offB + n * 512];
        #pragma unroll
        for (int m = 0; m < 2; ++m)
            #pragma unroll
            for (int n = 0; n < 4; ++n)
                acc[m][n] = __builtin_amdgcn_mfma_f32_16x16x32_bf16(
                    af[m], bfr[n], acc[m][n], 0, 0, 0);
        __syncthreads();
        cur ^= 1;
    }
#undef STAGE_64

    float* Cp = C + ((SPLITK > 1) ? (size_t)blockIdx.z * pstride : 0);
    const int rbase = m0 + wr + ((lane >> 4) << 2);
    const int cbase = n0 + wc + (lane & 15);
    #pragma unroll
    for (int n = 0; n < 4; ++n) {
        const int col = cbase + n * 16;
        if (col >= ncols) continue;
        const float bv = BIAS ? bias[col] : 0.f;
        #pragma unroll
        for (int m = 0; m < 2; ++m) {
            #pragma unroll
            for (int j = 0; j < 4; ++j) {
                float v = acc[m][n][j] + bv;
                if (ACT == 1) v = softplus_f(v);
                Cp[(size_t)(rbase + m * 16 + j) * ldc + col] = v;
            }
        }
    }
}

// ---------------------------------------------------------------------------
// Causal depthwise conv (K=4) + bias + silu on bf16 xc; 8 channels/thread.
// ---------------------------------------------------------------------------
__global__ __launch_bounds__(256) void conv_silu_k(
    const __bf16* __restrict__ xc, const float* __restrict__ cw,
    const float* __restrict__ cb, __bf16* __restrict__ xs_bf)
{
    const int idx = blockIdx.x * 256 + threadIdx.x;   // over L*DI/8
    const int l  = idx >> 8;
    const int d0 = (idx & 255) * 8;

    float r0[8] = {}, r1[8] = {}, r2[8] = {}, r3[8];
    bf16x8 v;
    if (l >= 3) { v = *(const bf16x8*)&xc[(size_t)(l-3)*DI + d0];
                  #pragma unroll
                  for (int j = 0; j < 8; ++j) r0[j] = (float)v[j]; }
    if (l >= 2) { v = *(const bf16x8*)&xc[(size_t)(l-2)*DI + d0];
                  #pragma unroll
                  for (int j = 0; j < 8; ++j) r1[j] = (float)v[j]; }
    if (l >= 1) { v = *(const bf16x8*)&xc[(size_t)(l-1)*DI + d0];
                  #pragma unroll
                  for (int j = 0; j < 8; ++j) r2[j] = (float)v[j]; }
    v = *(const bf16x8*)&xc[(size_t)l*DI + d0];
    #pragma unroll
    for (int j = 0; j < 8; ++j) r3[j] = (float)v[j];

    bf16x8 o;
    #pragma unroll
    for (int j = 0; j < 8; ++j) {
        const int d = d0 + j;
        float4 w = *(const float4*)&cw[d * 4];
        float a = cb[d];
        a = fmaf(r0[j], w.x, a);
        a = fmaf(r1[j], w.y, a);
        a = fmaf(r2[j], w.z, a);
        a = fmaf(r3[j], w.w, a);
        o[j] = (__bf16)silu_f(a);
    }
    *(bf16x8*)&xs_bf[(size_t)l*DI + d0] = o;
}

// ---------------------------------------------------------------------------
// Scan phase 1: per-(chunk, channel) local scan, h=0 start.
// ---------------------------------------------------------------------------
__global__ __launch_bounds__(256) void scan1_k(
    const float* __restrict__ delta, const __bf16* __restrict__ xs,
    const float* __restrict__ A_log, const float* __restrict__ xdbl,
    float* __restrict__ P, float* __restrict__ S)
{
    const int d = blockIdx.x * 256 + threadIdx.x;
    const int c = blockIdx.y;
    float A[NS];
    #pragma unroll
    for (int n = 0; n < NS; ++n) A[n] = -__expf(A_log[d * NS + n]);
    float h[NS] = {};
    float ap[NS];
    #pragma unroll
    for (int n = 0; n < NS; ++n) ap[n] = 1.f;

    const int l0 = c * CL;
    for (int l = l0; l < l0 + CL; ++l) {
        const float dt = delta[(size_t)l * DI + d];
        const float u  = (float)xs[(size_t)l * DI + d];
        const float du = dt * u;
        #pragma unroll
        for (int n = 0; n < NS; ++n) {
            const float Bn = xdbl[(size_t)l * 96 + RR + n];
            const float dA = __expf(dt * A[n]);
            h[n]  = fmaf(dA, h[n], du * Bn);
            ap[n] *= dA;
        }
    }
    const size_t base = ((size_t)c * DI + d) * NS;
    #pragma unroll
    for (int n = 0; n < NS; ++n) { P[base + n] = ap[n]; S[base + n] = h[n]; }
}

// ---------------------------------------------------------------------------
// Scan phase 2: sequential over NC chunks; exclusive prefix per (d,n).
// ---------------------------------------------------------------------------
__global__ __launch_bounds__(256) void scan2_k(
    const float* __restrict__ P, const float* __restrict__ S, float* __restrict__ Hp)
{
    const int idx = blockIdx.x * 256 + threadIdx.x;
    float h = 0.f;
    for (int c = 0; c < NC; ++c) {
        const size_t o = (size_t)c * DI * NS + idx;
        Hp[o] = h;
        h = fmaf(P[o], h, S[o]);
    }
}

// ---------------------------------------------------------------------------
// Scan phase 3: replay with prefix, y = (h.C + xs*D)*silu(res), write bf16.
// ---------------------------------------------------------------------------
__global__ __launch_bounds__(256) void scan3_k(
    const float* __restrict__ delta, const __bf16* __restrict__ xs,
    const float* __restrict__ A_log, const float* __restrict__ xdbl,
    const float* __restrict__ Hp, const __bf16* __restrict__ res_bf,
    const float* __restrict__ Dp, __bf16* __restrict__ y_bf)
{
    const int d = blockIdx.x * 256 + threadIdx.x;
    const int c = blockIdx.y;
    float A[NS];
    #pragma unroll
    for (int n = 0; n < NS; ++n) A[n] = -__expf(A_log[d * NS + n]);
    float h[NS];
    const size_t base = ((size_t)c * DI + d) * NS;
    #pragma unroll
    for (int n = 0; n < NS; ++n) h[n] = Hp[base + n];
    const float Dd = Dp[d];

    const int l0 = c * CL;
    for (int l = l0; l < l0 + CL; ++l) {
        const float dt = delta[(size_t)l * DI + d];
        const float u  = (float)xs[(size_t)l * DI + d];
        const float du = dt * u;
        float acc = 0.f;
        #pragma unroll
        for (int n = 0; n < NS; ++n) {
            const float Bn = xdbl[(size_t)l * 96 + RR + n];
            const float Cn = xdbl[(size_t)l * 96 + RR + NS + n];
            const float dA = __expf(dt * A[n]);
            h[n] = fmaf(dA, h[n], du * Bn);
            acc  = fmaf(h[n], Cn, acc);
        }
        float yv = fmaf(u, Dd, acc);
        const float r = (float)res_bf[(size_t)l * DI + d];
        yv *= silu_f(r);
        y_bf[(size_t)l * DI + d] = (__bf16)yv;
    }
}

// ---------------------------------------------------------------------------
extern "C" void kernel_launch(void* const* d_in, const int* in_sizes, int n_in,
                              void* d_out, int out_size, void* d_ws, size_t ws_size,
                              hipStream_t stream)
{
    const float* x        = (const float*)d_in[0];   // [L][H]
    const float* in_w     = (const float*)d_in[1];   // [2DI][H]
    const float* in_b     = (const float*)d_in[2];   // [2DI]
    const float* conv_w   = (const float*)d_in[3];   // [DI][1][4]
    const float* conv_b   = (const float*)d_in[4];   // [DI]
    const float* xproj_w  = (const float*)d_in[5];   // [96][DI]
    const float* dtproj_w = (const float*)d_in[6];   // [DI][R]
    const float* dtproj_b = (const float*)d_in[7];   // [DI]
    const float* A_log    = (const float*)d_in[8];   // [DI][N]
    const float* Dp       = (const float*)d_in[9];   // [DI]
    const float* outw     = (const float*)d_in[10];  // [H][DI]
    float* out = (float*)d_out;                      // [L][H]

    // fp32 workspace
    float* ws    = (float*)d_ws;
    float* delta = ws;                                 // [L][DI] 16MB (splitK partials alias)
    float* xdbl  = delta + (size_t)LL * DI;            // [L][96]
    float* P     = xdbl  + (size_t)LL * 96;            // [NC][DI][NS]
    float* S     = P     + (size_t)NC * DI * NS;
    float* Hp    = S     + (size_t)NC * DI * NS;
    float* xpart = delta;                              // [KSPL][L][96] = 12.6MB < 16MB
    // bf16 workspace
    __bf16* x_bf    = (__bf16*)(Hp + (size_t)NC * DI * NS);
    __bf16* inw_bf  = x_bf    + (size_t)LL * H_DIM;       // [2DI][H]
    __bf16* outw_bf = inw_bf  + (size_t)2 * DI * H_DIM;   // [H][DI]
    __bf16* dtw_bf  = outw_bf + (size_t)H_DIM * DI;       // [DI][R]
    __bf16* xdbl_bf = dtw_bf  + (size_t)DI * RR;          // [L][96]
    __bf16* y_bf    = xdbl_bf + (size_t)LL * 96;          // [L][DI]
    __bf16* xs_bf   = y_bf    + (size_t)LL * DI;          // [L][DI]
    __bf16* xc_bf   = xs_bf   + (size_t)LL * DI;          // [L][DI]
    __bf16* res_bf  = xc_bf   + (size_t)LL * DI;          // [L][DI]
    __bf16* xpw_pad = res_bf  + (size_t)LL * DI;          // [128][DI]

    const dim3 blk(256);

    // 0) all fp32->bf16 conversions + x_proj weight pad, one kernel
    convert_all_k<<<dim3(CUMT / 1024), blk, 0, stream>>>(
        x, in_w, outw, dtproj_w, xproj_w,
        x_bf, inw_bf, outw_bf, dtw_bf, xpw_pad);

    // 1) x_and_res = x @ in_proj_w^T + b -> bf16 xc | res  [L][2DI]
    gemm_inproj_k<<<dim3((2*DI)/128, LL/128), blk, 0, stream>>>(
        x_bf, inw_bf, in_b, xc_bf, res_bf);

    // 2) xs = silu(conv(xc) + conv_b)                      [L][DI] bf16
    conv_silu_k<<<dim3((LL*DI)/(8*256)), blk, 0, stream>>>(xc_bf, conv_w, conv_b, xs_bf);

    // 3) x_dbl = xs @ x_proj_w^T  (split-K MFMA + reduce)  [L][96] fp32+bf16
    gemm64_bf16_nt<0,0,KSPL,0><<<dim3(1, LL/64, KSPL), blk, 0, stream>>>(
        xs_bf, DI, xpw_pad, DI, nullptr, xpart, 96, 96, (size_t)LL * 96, DI);
    reduce_xdbl_k<<<dim3((LL * 96) / 256), blk, 0, stream>>>(xpart, xdbl, xdbl_bf);

    // 4) delta = softplus(x_dbl[:, :64] @ dt_proj_w^T + b) [L][DI] fp32
    gemm64_bf16_nt<1,1,1,1><<<dim3(DI/128, LL/64), blk, 0, stream>>>(
        xdbl_bf, 96, dtw_bf, RR, dtproj_b, delta, DI, DI, 0, RR);

    // 5-7) chunked scan; scan3 emits y as bf16
    scan1_k<<<dim3(DI/256, NC), blk, 0, stream>>>(delta, xs_bf, A_log, xdbl, P, S);
    scan2_k<<<dim3((DI*NS)/256), blk, 0, stream>>>(P, S, Hp);
    scan3_k<<<dim3(DI/256, NC), blk, 0, stream>>>(delta, xs_bf, A_log, xdbl, Hp, res_bf, Dp, y_bf);

    // 8) out = y @ out_proj_w^T                            [L][H]
    gemm64_bf16_nt<0,0,1,1><<<dim3(H_DIM/128, LL/64), blk, 0, stream>>>(
        y_bf, DI, outw_bf, DI, nullptr, out, H_DIM, H_DIM, 0, DI);
}

// Round 8
// 242.633 us; speedup vs baseline: 2.8015x; 1.1049x over previous
//
#include <hip/hip_runtime.h>
#include <hip/hip_bf16.h>
#include <math.h>

// Mamba forward, B=1, L=2048, H=1024, DI=2048, N=16, R=64, K=4
#define H_DIM 1024
#define DI    2048
#define NS    16
#define RR    64
#define LL    2048
#define NC    64   // chunks for the parallel scan
#define CL    32   // chunk length = LL/NC
#define KSPL  16   // split-K factor for x_proj

typedef __bf16 bf16x8 __attribute__((ext_vector_type(8)));
typedef __bf16 bf16x4 __attribute__((ext_vector_type(4)));
typedef float  f32x4  __attribute__((ext_vector_type(4)));

__device__ __forceinline__ float silu_f(float x)  { return x / (1.f + __expf(-x)); }
// Cheap softplus: hw exp/log only (log1pf libm slow path caused acc spills).
__device__ __forceinline__ float softplus_f(float x) {
    const float l = __logf(1.f + __expf(x));
    return x > 15.f ? x : l;
}

__device__ __forceinline__ void gload16(const void* g, void* l) {
    __builtin_amdgcn_global_load_lds(
        (const __attribute__((address_space(1))) void*)g,
        (__attribute__((address_space(3))) void*)l, 16, 0, 0);
}

__device__ __forceinline__ void f2b4(const float* __restrict__ in,
                                     __bf16* __restrict__ out)
{
    float4 v = *(const float4*)in;
    bf16x4 o;
    o[0] = (__bf16)v.x; o[1] = (__bf16)v.y; o[2] = (__bf16)v.z; o[3] = (__bf16)v.w;
    *(bf16x4*)out = o;
}

// XCD-aware chunked swizzle over a 2D grid (requires nwg % 8 == 0).
__device__ __forceinline__ void xcd_swz(int nx, int ny, int& bx, int& by)
{
    const int nwg = nx * ny;
    const int bid = by * nx + bx;
    const int cpx = nwg >> 3;
    const int s   = (bid & 7) * cpx + (bid >> 3);
    bx = s % nx;  by = s / nx;
}

// ---------------------------------------------------------------------------
// One fused conversion kernel: x, in_w, outw, dtw (f2b) + x_proj_w pad.
// ---------------------------------------------------------------------------
#define SEG0 (LL * H_DIM)          // x
#define SEG1 (2 * DI * H_DIM)      // in_w
#define SEG2 (H_DIM * DI)          // outw
#define SEG3 (DI * RR)             // dtw
#define SEG4 (128 * DI)            // xpw_pad
#define CUM0 SEG0
#define CUM1 (CUM0 + SEG1)
#define CUM2 (CUM1 + SEG2)
#define CUM3 (CUM2 + SEG3)
#define CUMT (CUM3 + SEG4)

__global__ __launch_bounds__(256) void convert_all_k(
    const float* __restrict__ x,    const float* __restrict__ in_w,
    const float* __restrict__ outw, const float* __restrict__ dtw,
    const float* __restrict__ xpw,
    __bf16* __restrict__ x_bf,    __bf16* __restrict__ inw_bf,
    __bf16* __restrict__ outw_bf, __bf16* __restrict__ dtw_bf,
    __bf16* __restrict__ xpw_pad)
{
    const int i = (blockIdx.x * 256 + threadIdx.x) * 4;
    if (i < CUM0) {
        f2b4(x + i, x_bf + i);
    } else if (i < CUM1) {
        const int o = i - CUM0;  f2b4(in_w + o, inw_bf + o);
    } else if (i < CUM2) {
        const int o = i - CUM1;  f2b4(outw + o, outw_bf + o);
    } else if (i < CUM3) {
        const int o = i - CUM2;  f2b4(dtw + o, dtw_bf + o);
    } else if (i < CUMT) {
        const int o = i - CUM3;           // over [128][2048]
        const int row = o >> 11;
        if (row < 96) {
            f2b4(xpw + o, xpw_pad + o);
        } else {
            bf16x4 z; z[0] = z[1] = z[2] = z[3] = (__bf16)0.f;
            *(bf16x4*)&xpw_pad[o] = z;
        }
    }
}

// sum the KSPL split-K partials of x_dbl; emit fp32 + bf16
__global__ __launch_bounds__(256) void reduce_xdbl_k(
    const float* __restrict__ part, float* __restrict__ xdbl,
    __bf16* __restrict__ xdbl_bf)
{
    const int idx = blockIdx.x * 256 + threadIdx.x;   // over LL*96
    float s = 0.f;
    #pragma unroll
    for (int z = 0; z < KSPL; ++z) s += part[(size_t)z * (LL * 96) + idx];
    xdbl[idx] = s;
    xdbl_bf[idx] = (__bf16)s;
}

// sum the 2 out_proj split-K partials -> fp32 out (float4 vectorized)
__global__ __launch_bounds__(256) void reduce_out_k(
    const float* __restrict__ part, float* __restrict__ out)
{
    const int i = (blockIdx.x * 256 + threadIdx.x) * 4;   // over LL*H
    f32x4 a = *(const f32x4*)&part[i];
    f32x4 b = *(const f32x4*)&part[(size_t)LL * H_DIM + i];
    *(f32x4*)&out[i] = a + b;
}

// ---------------------------------------------------------------------------
// in_proj GEMM: 64x128 tile, 2-phase dbuf LDS, grid (4096/128, 2048/64) =
// (32,32) = 1024 blocks (4/CU). Writes bf16 xc / res split halves directly.
// ---------------------------------------------------------------------------
__global__ __launch_bounds__(256) void gemm_inproj_k(
    const __bf16* __restrict__ A,        // [L][H]
    const __bf16* __restrict__ W,        // [2DI][H]
    const float* __restrict__ bias,
    __bf16* __restrict__ xc_bf,          // [L][DI]
    __bf16* __restrict__ res_bf)         // [L][DI]
{
    __shared__ __bf16 smA[2][64 * 32];
    __shared__ __bf16 smB[2][128 * 32];
    const int t    = threadIdx.x;
    const int lane = t & 63;
    int bx = blockIdx.x, by = blockIdx.y;
    xcd_swz(32, 32, bx, by);
    const int m0 = by * 64, n0 = bx * 128;
    const int wr = ((t >> 6) >> 1) * 32;
    const int wc = ((t >> 6) & 1) * 64;

    const int srow = t >> 2;
    const int skof = (t & 3) * 8;
    const int lds_base = (t >> 6) * 512;

    const int offA = (wr + (lane & 15)) * 32 + ((lane >> 4) * 8);
    const int offB = (wc + (lane & 15)) * 32 + ((lane >> 4) * 8);

    f32x4 acc[2][4] = {};

#define STAGE_IP(buf, k0)                                                          \
    do {                                                                           \
        gload16(A + (size_t)(m0 + srow)      * H_DIM + (k0) + skof, &smA[buf][lds_base]);        \
        gload16(W + (size_t)(n0 + srow)      * H_DIM + (k0) + skof, &smB[buf][lds_base]);        \
        gload16(W + (size_t)(n0 + 64 + srow) * H_DIM + (k0) + skof, &smB[buf][2048 + lds_base]); \
    } while (0)

    STAGE_IP(0, 0);
    __syncthreads();
    int cur = 0;
    for (int k0 = 0; k0 < H_DIM; k0 += 32) {
        if (k0 + 32 < H_DIM) STAGE_IP(cur ^ 1, k0 + 32);

        bf16x8 af[2], bfr[4];
        #pragma unroll
        for (int m = 0; m < 2; ++m) af[m]  = *(const bf16x8*)&smA[cur][offA + m * 512];
        #pragma unroll
        for (int n = 0; n < 4; ++n) bfr[n] = *(const bf16x8*)&smB[cur][offB + n * 512];
        #pragma unroll
        for (int m = 0; m < 2; ++m)
            #pragma unroll
            for (int n = 0; n < 4; ++n)
                acc[m][n] = __builtin_amdgcn_mfma_f32_16x16x32_bf16(
                    af[m], bfr[n], acc[m][n], 0, 0, 0);
        __syncthreads();
        cur ^= 1;
    }
#undef STAGE_IP

    // entire block's col range is on one side of DI (n0 is 128-aligned)
    __bf16* outp = (n0 < DI) ? xc_bf : res_bf;
    const int ncol0 = (n0 < DI) ? n0 : n0 - DI;
    const int rbase = m0 + wr + ((lane >> 4) << 2);
    const int cbase = ncol0 + wc + (lane & 15);
    #pragma unroll
    for (int n = 0; n < 4; ++n) {
        const int col = cbase + n * 16;
        const float bv = bias[(n0 < DI ? 0 : DI) + col];
        #pragma unroll
        for (int m = 0; m < 2; ++m)
            #pragma unroll
            for (int j = 0; j < 4; ++j)
                outp[(size_t)(rbase + m * 16 + j) * DI + col] =
                    (__bf16)(acc[m][n][j] + bv);
    }
}

// ---------------------------------------------------------------------------
// bf16 MFMA GEMM, 64x128 tile, 2-phase dbuf (out_proj / dt_proj / x_proj).
// grid = (N/128, M/64, SPLITK). ncols guards C writes (padded W rows).
// ---------------------------------------------------------------------------
template<int BIAS, int ACT, int SPLITK, int SWZ>
__global__ __launch_bounds__(256) void gemm64_bf16_nt(
    const __bf16* __restrict__ A, int lda,
    const __bf16* __restrict__ W, int ldw,
    const float* __restrict__ bias,
    float* __restrict__ C, int ldc, int ncols, size_t pstride,
    int K)
{
    __shared__ __bf16 smA[2][64 * 32];
    __shared__ __bf16 smB[2][128 * 32];
    const int t    = threadIdx.x;
    const int lane = t & 63;
    int bx = blockIdx.x, by = blockIdx.y;
    if (SWZ) xcd_swz(gridDim.x, gridDim.y, bx, by);
    const int m0 = by * 64, n0 = bx * 128;
    const int wr = ((t >> 6) >> 1) * 32;
    const int wc = ((t >> 6) & 1) * 64;

    const int srow = t >> 2;
    const int skof = (t & 3) * 8;
    const int lds_base = (t >> 6) * 512;

    const int offA = (wr + (lane & 15)) * 32 + ((lane >> 4) * 8);
    const int offB = (wc + (lane & 15)) * 32 + ((lane >> 4) * 8);

    const int kseg  = K / SPLITK;
    const int kbase = (SPLITK > 1) ? blockIdx.z * kseg : 0;
    const int kend  = kbase + kseg;

    f32x4 acc[2][4] = {};

#define STAGE_64(buf, k0)                                                          \
    do {                                                                           \
        gload16(A + (size_t)(m0 + srow)      * lda + (k0) + skof, &smA[buf][lds_base]);        \
        gload16(W + (size_t)(n0 + srow)      * ldw + (k0) + skof, &smB[buf][lds_base]);        \
        gload16(W + (size_t)(n0 + 64 + srow) * ldw + (k0) + skof, &smB[buf][2048 + lds_base]); \
    } while (0)

    STAGE_64(0, kbase);
    __syncthreads();
    int cur = 0;
    for (int k0 = kbase; k0 < kend; k0 += 32) {
        if (k0 + 32 < kend) STAGE_64(cur ^ 1, k0 + 32);

        bf16x8 af[2], bfr[4];
        #pragma unroll
        for (int m = 0; m < 2; ++m) af[m]  = *(const bf16x8*)&smA[cur][offA + m * 512];
        #pragma unroll
        for (int n = 0; n < 4; ++n) bfr[n] = *(const bf16x8*)&smB[cur][offB + n * 512];
        #pragma unroll
        for (int m = 0; m < 2; ++m)
            #pragma unroll
            for (int n = 0; n < 4; ++n)
                acc[m][n] = __builtin_amdgcn_mfma_f32_16x16x32_bf16(
                    af[m], bfr[n], acc[m][n], 0, 0, 0);
        __syncthreads();
        cur ^= 1;
    }
#undef STAGE_64

    float* Cp = C + ((SPLITK > 1) ? (size_t)blockIdx.z * pstride : 0);
    const int rbase = m0 + wr + ((lane >> 4) << 2);
    const int cbase = n0 + wc + (lane & 15);
    #pragma unroll
    for (int n = 0; n < 4; ++n) {
        const int col = cbase + n * 16;
        if (col >= ncols) continue;
        const float bv = BIAS ? bias[col] : 0.f;
        #pragma unroll
        for (int m = 0; m < 2; ++m) {
            #pragma unroll
            for (int j = 0; j < 4; ++j) {
                float v = acc[m][n][j] + bv;
                if (ACT == 1) v = softplus_f(v);
                Cp[(size_t)(rbase + m * 16 + j) * ldc + col] = v;
            }
        }
    }
}

// ---------------------------------------------------------------------------
// Causal depthwise conv (K=4) + bias + silu on bf16 xc; 8 channels/thread.
// ---------------------------------------------------------------------------
__global__ __launch_bounds__(256) void conv_silu_k(
    const __bf16* __restrict__ xc, const float* __restrict__ cw,
    const float* __restrict__ cb, __bf16* __restrict__ xs_bf)
{
    const int idx = blockIdx.x * 256 + threadIdx.x;   // over L*DI/8
    const int l  = idx >> 8;
    const int d0 = (idx & 255) * 8;

    float r0[8] = {}, r1[8] = {}, r2[8] = {}, r3[8];
    bf16x8 v;
    if (l >= 3) { v = *(const bf16x8*)&xc[(size_t)(l-3)*DI + d0];
                  #pragma unroll
                  for (int j = 0; j < 8; ++j) r0[j] = (float)v[j]; }
    if (l >= 2) { v = *(const bf16x8*)&xc[(size_t)(l-2)*DI + d0];
                  #pragma unroll
                  for (int j = 0; j < 8; ++j) r1[j] = (float)v[j]; }
    if (l >= 1) { v = *(const bf16x8*)&xc[(size_t)(l-1)*DI + d0];
                  #pragma unroll
                  for (int j = 0; j < 8; ++j) r2[j] = (float)v[j]; }
    v = *(const bf16x8*)&xc[(size_t)l*DI + d0];
    #pragma unroll
    for (int j = 0; j < 8; ++j) r3[j] = (float)v[j];

    bf16x8 o;
    #pragma unroll
    for (int j = 0; j < 8; ++j) {
        const int d = d0 + j;
        float4 w = *(const float4*)&cw[d * 4];
        float a = cb[d];
        a = fmaf(r0[j], w.x, a);
        a = fmaf(r1[j], w.y, a);
        a = fmaf(r2[j], w.z, a);
        a = fmaf(r3[j], w.w, a);
        o[j] = (__bf16)silu_f(a);
    }
    *(bf16x8*)&xs_bf[(size_t)l*DI + d0] = o;
}

// ---------------------------------------------------------------------------
// Scan phase 1: per-(chunk, channel) local scan, h=0 start.
// ---------------------------------------------------------------------------
__global__ __launch_bounds__(256) void scan1_k(
    const float* __restrict__ delta, const __bf16* __restrict__ xs,
    const float* __restrict__ A_log, const float* __restrict__ xdbl,
    float* __restrict__ P, float* __restrict__ S)
{
    const int d = blockIdx.x * 256 + threadIdx.x;
    const int c = blockIdx.y;
    float A[NS];
    #pragma unroll
    for (int n = 0; n < NS; ++n) A[n] = -__expf(A_log[d * NS + n]);
    float h[NS] = {};
    float ap[NS];
    #pragma unroll
    for (int n = 0; n < NS; ++n) ap[n] = 1.f;

    const int l0 = c * CL;
    for (int l = l0; l < l0 + CL; ++l) {
        const float dt = delta[(size_t)l * DI + d];
        const float u  = (float)xs[(size_t)l * DI + d];
        const float du = dt * u;
        #pragma unroll
        for (int n = 0; n < NS; ++n) {
            const float Bn = xdbl[(size_t)l * 96 + RR + n];
            const float dA = __expf(dt * A[n]);
            h[n]  = fmaf(dA, h[n], du * Bn);
            ap[n] *= dA;
        }
    }
    const size_t base = ((size_t)c * DI + d) * NS;
    #pragma unroll
    for (int n = 0; n < NS; ++n) { P[base + n] = ap[n]; S[base + n] = h[n]; }
}

// ---------------------------------------------------------------------------
// Scan phase 2: sequential over NC chunks; exclusive prefix per (d,n).
// ---------------------------------------------------------------------------
__global__ __launch_bounds__(256) void scan2_k(
    const float* __restrict__ P, const float* __restrict__ S, float* __restrict__ Hp)
{
    const int idx = blockIdx.x * 256 + threadIdx.x;
    float h = 0.f;
    for (int c = 0; c < NC; ++c) {
        const size_t o = (size_t)c * DI * NS + idx;
        Hp[o] = h;
        h = fmaf(P[o], h, S[o]);
    }
}

// ---------------------------------------------------------------------------
// Scan phase 3: replay with prefix, y = (h.C + xs*D)*silu(res), write bf16.
// ---------------------------------------------------------------------------
__global__ __launch_bounds__(256) void scan3_k(
    const float* __restrict__ delta, const __bf16* __restrict__ xs,
    const float* __restrict__ A_log, const float* __restrict__ xdbl,
    const float* __restrict__ Hp, const __bf16* __restrict__ res_bf,
    const float* __restrict__ Dp, __bf16* __restrict__ y_bf)
{
    const int d = blockIdx.x * 256 + threadIdx.x;
    const int c = blockIdx.y;
    float A[NS];
    #pragma unroll
    for (int n = 0; n < NS; ++n) A[n] = -__expf(A_log[d * NS + n]);
    float h[NS];
    const size_t base = ((size_t)c * DI + d) * NS;
    #pragma unroll
    for (int n = 0; n < NS; ++n) h[n] = Hp[base + n];
    const float Dd = Dp[d];

    const int l0 = c * CL;
    for (int l = l0; l < l0 + CL; ++l) {
        const float dt = delta[(size_t)l * DI + d];
        const float u  = (float)xs[(size_t)l * DI + d];
        const float du = dt * u;
        float acc = 0.f;
        #pragma unroll
        for (int n = 0; n < NS; ++n) {
            const float Bn = xdbl[(size_t)l * 96 + RR + n];
            const float Cn = xdbl[(size_t)l * 96 + RR + NS + n];
            const float dA = __expf(dt * A[n]);
            h[n] = fmaf(dA, h[n], du * Bn);
            acc  = fmaf(h[n], Cn, acc);
        }
        float yv = fmaf(u, Dd, acc);
        const float r = (float)res_bf[(size_t)l * DI + d];
        yv *= silu_f(r);
        y_bf[(size_t)l * DI + d] = (__bf16)yv;
    }
}

// ---------------------------------------------------------------------------
extern "C" void kernel_launch(void* const* d_in, const int* in_sizes, int n_in,
                              void* d_out, int out_size, void* d_ws, size_t ws_size,
                              hipStream_t stream)
{
    const float* x        = (const float*)d_in[0];   // [L][H]
    const float* in_w     = (const float*)d_in[1];   // [2DI][H]
    const float* in_b     = (const float*)d_in[2];   // [2DI]
    const float* conv_w   = (const float*)d_in[3];   // [DI][1][4]
    const float* conv_b   = (const float*)d_in[4];   // [DI]
    const float* xproj_w  = (const float*)d_in[5];   // [96][DI]
    const float* dtproj_w = (const float*)d_in[6];   // [DI][R]
    const float* dtproj_b = (const float*)d_in[7];   // [DI]
    const float* A_log    = (const float*)d_in[8];   // [DI][N]
    const float* Dp       = (const float*)d_in[9];   // [DI]
    const float* outw     = (const float*)d_in[10];  // [H][DI]
    float* out = (float*)d_out;                      // [L][H]

    // fp32 workspace
    float* ws    = (float*)d_ws;
    float* delta = ws;                                 // [L][DI] 16MB (splitK partials alias)
    float* xdbl  = delta + (size_t)LL * DI;            // [L][96]
    float* P     = xdbl  + (size_t)LL * 96;            // [NC][DI][NS] 8MB
    float* S     = P     + (size_t)NC * DI * NS;       // 8MB
    float* Hp    = S     + (size_t)NC * DI * NS;       // 8MB
    float* opart = Hp    + (size_t)NC * DI * NS;       // [2][L][H] 16MB
    float* xpart = delta;                              // [KSPL][L][96] = 12.6MB < 16MB
    // bf16 workspace
    __bf16* x_bf    = (__bf16*)(opart + (size_t)2 * LL * H_DIM);
    __bf16* inw_bf  = x_bf    + (size_t)LL * H_DIM;       // [2DI][H]
    __bf16* outw_bf = inw_bf  + (size_t)2 * DI * H_DIM;   // [H][DI]
    __bf16* dtw_bf  = outw_bf + (size_t)H_DIM * DI;       // [DI][R]
    __bf16* xdbl_bf = dtw_bf  + (size_t)DI * RR;          // [L][96]
    __bf16* y_bf    = xdbl_bf + (size_t)LL * 96;          // [L][DI]
    __bf16* xs_bf   = y_bf    + (size_t)LL * DI;          // [L][DI]
    __bf16* xc_bf   = xs_bf   + (size_t)LL * DI;          // [L][DI]
    __bf16* res_bf  = xc_bf   + (size_t)LL * DI;          // [L][DI]
    __bf16* xpw_pad = res_bf  + (size_t)LL * DI;          // [128][DI]

    const dim3 blk(256);

    // 0) all fp32->bf16 conversions + x_proj weight pad, one kernel
    convert_all_k<<<dim3(CUMT / 1024), blk, 0, stream>>>(
        x, in_w, outw, dtproj_w, xproj_w,
        x_bf, inw_bf, outw_bf, dtw_bf, xpw_pad);

    // 1) x_and_res = x @ in_proj_w^T + b -> bf16 xc | res  [L][2DI]
    //    64x128 tile, grid (32,32) = 1024 blocks (4/CU)
    gemm_inproj_k<<<dim3((2*DI)/128, LL/64), blk, 0, stream>>>(
        x_bf, inw_bf, in_b, xc_bf, res_bf);

    // 2) xs = silu(conv(xc) + conv_b)                      [L][DI] bf16
    conv_silu_k<<<dim3((LL*DI)/(8*256)), blk, 0, stream>>>(xc_bf, conv_w, conv_b, xs_bf);

    // 3) x_dbl = xs @ x_proj_w^T  (split-K MFMA + reduce)  [L][96] fp32+bf16
    gemm64_bf16_nt<0,0,KSPL,0><<<dim3(1, LL/64, KSPL), blk, 0, stream>>>(
        xs_bf, DI, xpw_pad, DI, nullptr, xpart, 96, 96, (size_t)LL * 96, DI);
    reduce_xdbl_k<<<dim3((LL * 96) / 256), blk, 0, stream>>>(xpart, xdbl, xdbl_bf);

    // 4) delta = softplus(x_dbl[:, :64] @ dt_proj_w^T + b) [L][DI] fp32
    gemm64_bf16_nt<1,1,1,1><<<dim3(DI/128, LL/64), blk, 0, stream>>>(
        xdbl_bf, 96, dtw_bf, RR, dtproj_b, delta, DI, DI, 0, RR);

    // 5-7) chunked scan (NC=64); scan3 emits y as bf16
    scan1_k<<<dim3(DI/256, NC), blk, 0, stream>>>(delta, xs_bf, A_log, xdbl, P, S);
    scan2_k<<<dim3((DI*NS)/256), blk, 0, stream>>>(P, S, Hp);
    scan3_k<<<dim3(DI/256, NC), blk, 0, stream>>>(delta, xs_bf, A_log, xdbl, Hp, res_bf, Dp, y_bf);

    // 8) out = y @ out_proj_w^T  (split-K=2 + reduce)      [L][H]
    gemm64_bf16_nt<0,0,2,1><<<dim3(H_DIM/128, LL/64, 2), blk, 0, stream>>>(
        y_bf, DI, outw_bf, DI, nullptr, opart, H_DIM, H_DIM, (size_t)LL * H_DIM, DI);
    reduce_out_k<<<dim3((LL * H_DIM) / 1024), blk, 0, stream>>>(opart, out);
}